// Round 8
// baseline (989.213 us; speedup 1.0000x reference)
//
#include <hip/hip_runtime.h>

#define NB 64
#define NN 256
#define IND 7
#define HIDD 64
#define OUTD 32
#define EPG 8192
#define ETOT 524288
#define CAPQ 2600     // CSR capacity per 64-dst quarter (mean 2112, ~12 sigma)
#define SRCPAD 2624   // CAPQ rounded to 16

typedef _Float16 f16;
typedef f16 f16x2 __attribute__((ext_vector_type(2)));
typedef f16 f16x4 __attribute__((ext_vector_type(4)));
typedef f16 f16x8 __attribute__((ext_vector_type(8)));
typedef float f32x4 __attribute__((ext_vector_type(4)));

// ---------------- block reductions for 16-wave blocks ----------------
__device__ __forceinline__ float bsum16(float v, float* rb){
#pragma unroll
  for (int o = 32; o > 0; o >>= 1) v += __shfl_xor(v, o, 64);
  __syncthreads();
  if ((threadIdx.x & 63) == 0) rb[threadIdx.x >> 6] = v;
  __syncthreads();
  float s = 0.f;
#pragma unroll
  for (int i = 0; i < 16; i++) s += rb[i];
  return s;
}
__device__ __forceinline__ float bmin16(float v, float* rb){
#pragma unroll
  for (int o = 32; o > 0; o >>= 1) v = fminf(v, __shfl_xor(v, o, 64));
  __syncthreads();
  if ((threadIdx.x & 63) == 0) rb[threadIdx.x >> 6] = v;
  __syncthreads();
  float s = rb[0];
#pragma unroll
  for (int i = 1; i < 16; i++) s = fminf(s, rb[i]);
  return s;
}
__device__ __forceinline__ float bmax16(float v, float* rb){
#pragma unroll
  for (int o = 32; o > 0; o >>= 1) v = fmaxf(v, __shfl_xor(v, o, 64));
  __syncthreads();
  if ((threadIdx.x & 63) == 0) rb[threadIdx.x >> 6] = v;
  __syncthreads();
  float s = rb[0];
#pragma unroll
  for (int i = 1; i < 16; i++) s = fmaxf(s, rb[i]);
  return s;
}

__device__ __forceinline__ f16x2 lrelu2(f16x2 s){
  const f16x2 k = {(f16)0.2f, (f16)0.2f};
  return __builtin_elementwise_max(s, s * k);
}
__device__ __forceinline__ f16x2 shfl_h2(f16x2 v, int lane){
  int i = __builtin_bit_cast(int, v);
  i = __shfl(i, lane, 64);
  return __builtin_bit_cast(f16x2, i);
}
// order-preserving float<->uint keys for min/max merging
__device__ __forceinline__ unsigned fkey(float f){
  unsigned b = __float_as_uint(f);
  return (b & 0x80000000u) ? ~b : (b | 0x80000000u);
}
__device__ __forceinline__ float fkinv(unsigned k){
  unsigned b = (k & 0x80000000u) ? (k ^ 0x80000000u) : ~k;
  return __uint_as_float(b);
}
__device__ __forceinline__ unsigned ldacq(const unsigned* p){
  return __hip_atomic_load(p, __ATOMIC_ACQUIRE, __HIP_MEMORY_SCOPE_AGENT);
}

// ---------------- GAT layer 1 + CSR build (fused, single edge read) --------
// grid 512: (gs=bid>>2, quarter=bid&3 -> 64 dsts), 512 thr, 8 thr/dst.
__global__ __launch_bounds__(512, 4) void gat1(
    const float* __restrict__ x1, const float* __restrict__ x2,
    const int* __restrict__ e1, const int* __restrict__ e2,
    const float* __restrict__ Wl, const float* __restrict__ Wr,
    const float* __restrict__ bl, const float* __restrict__ br,
    const float* __restrict__ att, const float* __restrict__ bias,
    f16* __restrict__ hmid,
    int* __restrict__ meta, unsigned char* __restrict__ srcs)
{
  __shared__ __align__(16) f16 xl_s[256 * 72];   // rows padded to 144B
  __shared__ float sc_s[CAPQ];
  __shared__ unsigned int src_su[SRCPAD / 4];
  __shared__ int deg_s[64], start_s[64], cnt_s[64];
  __shared__ unsigned char perm[64];
  unsigned char* src_s = (unsigned char*)src_su;

  const int bid = blockIdx.x;
  const int gs = bid >> 2, lo = (bid & 3) * 64;
  const int side = gs >> 6, g = gs & 63;
  const float* x = side ? x2 : x1;
  const int* eb = side ? e2 : e1;
  const int* es = eb + g * EPG;
  const int* ed = eb + ETOT + g * EPG;
  const int t = threadIdx.x;

  if (t < 64) deg_s[t] = 0;

  // ---- single global edge read -> registers (packed dst<<8|src)
  unsigned short epk[17];
  int nE = 0;
#pragma unroll
  for (int i = 0; i < 17; i++){
    int e = t + i * 512;
    if (e < EPG + 256){
      int sl, dl;
      if (e < EPG){ sl = es[e] & 255; dl = ed[e] & 255; }
      else { sl = dl = e - EPG; }
      epk[i] = (unsigned short)((dl << 8) | sl);
      nE = i + 1;
    }
  }

  // ---- xl = x@Wl + bl: thread t -> node t>>1, dim-half t&1 (32 dims), f16 LDS
  {
    const int node = t >> 1, dh = t & 1;
    float xv[IND];
    const float* xr_ = x + (g * 256 + node) * IND;
#pragma unroll
    for (int k = 0; k < IND; k++) xv[k] = xr_[k];
#pragma unroll
    for (int ch = 0; ch < 4; ch++){
      f16x8 o;
#pragma unroll
      for (int j = 0; j < 8; j++){
        int dd = dh * 32 + ch * 8 + j;
        float a = bl[dd];
#pragma unroll
        for (int k = 0; k < IND; k++) a = fmaf(xv[k], Wl[k * HIDD + dd], a);
        o[j] = (f16)a;
      }
      *(f16x8*)&xl_s[node * 72 + dh * 32 + ch * 8] = o;
    }
  }
  __syncthreads();   // deg zero + xl_s visible

  // ---- CSR count pass (from regs)
#pragma unroll
  for (int i = 0; i < 17; i++) if (i < nE){
    int r = (epk[i] >> 8) - lo;
    if ((unsigned)r < 64u) atomicAdd(&deg_s[r], 1);
  }
  __syncthreads();
  // ---- scan + meta + degree-sort permutation
  if (t < 64){
    int v = deg_s[t], s = v;
#pragma unroll
    for (int off = 1; off < 64; off <<= 1){
      int u = __shfl_up(s, off, 64);
      if (t >= off) s += u;
    }
    start_s[t] = s - v;
    cnt_s[t] = s - v;
    meta[bid * 128 + t] = s - v;
    meta[bid * 128 + 64 + t] = v;
    int r = 0;
#pragma unroll 8
    for (int j = 0; j < 64; j++){
      int dj = deg_s[j];
      r += (dj < v) || (dj == v && j < t);
    }
    perm[r] = (unsigned char)t;
  }
  __syncthreads();
  // ---- fill pass (from regs)
#pragma unroll
  for (int i = 0; i < 17; i++) if (i < nE){
    int dl = epk[i] >> 8, r = dl - lo;
    if ((unsigned)r < 64u){
      int p = atomicAdd(&cnt_s[r], 1);
      if (p < CAPQ) src_s[p] = (unsigned char)(epk[i] & 255);
    }
  }
  __syncthreads();
  // ---- dump CSR srcs to global for gat2 (coalesced u32)
  {
    int ttl = start_s[63] + deg_s[63];
    if (ttl > CAPQ) ttl = CAPQ;
    unsigned int* gsrc = (unsigned int*)(srcs + (size_t)bid * SRCPAD);
    int nw = (ttl + 3) >> 2;
    for (int i = t; i < nw; i += 512) gsrc[i] = src_su[i];
  }

  // ---- 8 threads/dst (degree-sorted): my 8 xr dims, assemble 64 via shfl
  const int pairi = perm[t >> 3], sub = t & 7, ln = lo + pairi;
  f16x2 m[4], am[4];
  {
    float xv[IND];
    const float* xq = x + (g * 256 + ln) * IND;
#pragma unroll
    for (int k = 0; k < IND; k++) xv[k] = xq[k];
#pragma unroll
    for (int c = 0; c < 4; c++){
#pragma unroll
      for (int u = 0; u < 2; u++){
        int dd = sub * 8 + 2 * c + u;
        float a = br[dd];
#pragma unroll
        for (int k = 0; k < IND; k++) a = fmaf(xv[k], Wr[k * HIDD + dd], a);
        m[c][u] = (f16)a;
        am[c][u] = (f16)att[dd];
      }
    }
  }
  f16x2 xrh[32], atth[32];
  {
    const int base = (t & 63) & ~7;
#pragma unroll
    for (int ss = 0; ss < 8; ss++){
#pragma unroll
      for (int c = 0; c < 4; c++){
        xrh[ss * 4 + c] = shfl_h2(m[c], base + ss);
        atth[ss * 4 + c] = shfl_h2(am[c], base + ss);
      }
    }
  }

  // ---- scores: edge-split (thread handles every-8th edge, full 64 dims)
  const int s0 = start_s[pairi];
  int sE = s0 + deg_s[pairi];
  if (sE > CAPQ) sE = CAPQ;
  float lmax = -3.0e38f;
  for (int idx = s0 + sub; idx < sE; idx += 8){
    int sl = src_s[idx];
    const f16x8* rp = (const f16x8*)&xl_s[(unsigned)sl * 72];
    float accs[4] = {0.f, 0.f, 0.f, 0.f};
#pragma unroll
    for (int blk = 0; blk < 8; blk++){
      f16x8 rv = rp[blk];
#pragma unroll
      for (int u = 0; u < 4; u++){
        f16x2 v = {rv[2 * u], rv[2 * u + 1]};
        v = v + xrh[blk * 4 + u];
        accs[u] = __builtin_amdgcn_fdot2(lrelu2(v), atth[blk * 4 + u], accs[u], false);
      }
    }
    float sc = (accs[0] + accs[1]) + (accs[2] + accs[3]);
    sc_s[idx] = sc;
    lmax = fmaxf(lmax, sc);
  }
  lmax = fmaxf(lmax, __shfl_xor(lmax, 1, 64));
  lmax = fmaxf(lmax, __shfl_xor(lmax, 2, 64));
  lmax = fmaxf(lmax, __shfl_xor(lmax, 4, 64));
  const float smax = lmax;
  // ---- softmax weights
  float ssum = 0.f;
  for (int idx = s0 + sub; idx < sE; idx += 8){
    float w = __expf(sc_s[idx] - smax);
    ssum += w;
    sc_s[idx] = w;
  }
  ssum += __shfl_xor(ssum, 1, 64);
  ssum += __shfl_xor(ssum, 2, 64);
  ssum += __shfl_xor(ssum, 4, 64);
  float inv = 1.f / ssum;
  // ---- aggregate alpha * xl[src], dim-split 8 ways
  float acc[8];
#pragma unroll
  for (int c = 0; c < 8; c++) acc[c] = 0.f;
  {
    int sl = (s0 < sE) ? src_s[s0] : 0;
    f16x8 row = *(const f16x8*)&xl_s[(unsigned)sl * 72 + sub * 8];
    for (int idx = s0; idx < sE; idx++){
      int sln = (idx + 1 < sE) ? src_s[idx + 1] : 0;
      f16x8 rown = *(const f16x8*)&xl_s[(unsigned)sln * 72 + sub * 8];
      float w = sc_s[idx];
#pragma unroll
      for (int c = 0; c < 8; c++) acc[c] = fmaf(w, (float)row[c], acc[c]);
      row = rown;
    }
  }
  f16x8 o;
#pragma unroll
  for (int c = 0; c < 8; c++)
    o[c] = (f16)fmaxf(acc[c] * inv + bias[sub * 8 + c], 0.f);
  *(f16x8*)(hmid + (size_t)(gs * 256 + ln) * 64 + sub * 8) = o;
}

// ---------------- GAT layer 2 + lin2 (fused, degree-sorted) ----------------
__global__ __launch_bounds__(512, 4) void gat2(
    const int* __restrict__ meta, const unsigned char* __restrict__ srcs,
    const f16* __restrict__ hmid,
    const float* __restrict__ Wl, const float* __restrict__ Wr,
    const float* __restrict__ bl, const float* __restrict__ br,
    const float* __restrict__ att, const float* __restrict__ bias,
    f16* __restrict__ hout, unsigned* __restrict__ cnt)
{
  __shared__ __align__(16) f16 xl_s[256 * 40];   // rows padded to 80B
  __shared__ __align__(16) f16 xr_s[64 * 40];
  __shared__ float sc_s[CAPQ];
  __shared__ unsigned int src_su[SRCPAD / 4];
  __shared__ int start_s[64], deg_s[64];
  __shared__ unsigned char perm[64];
  unsigned char* src_s = (unsigned char*)src_su;

  const int bid = blockIdx.x;
  const int gs = bid >> 2, lo = (bid & 3) * 64;
  const int t = threadIdx.x;

  // ---- zero the simfused arrival counters (bid 0 only; poisoned each call)
  if (bid == 0 && t < 128) cnt[t] = 0u;

  // ---- CSR load (global -> LDS)
  if (t < 64){
    start_s[t] = meta[bid * 128 + t];
    deg_s[t] = meta[bid * 128 + 64 + t];
  }
  {
    int ttl = meta[bid * 128 + 63] + meta[bid * 128 + 64 + 63];
    if (ttl > CAPQ) ttl = CAPQ;
    const unsigned int* gsrc = (const unsigned int*)(srcs + (size_t)bid * SRCPAD);
    int nw = (ttl + 3) >> 2;
    for (int i = t; i < nw; i += 512) src_su[i] = gsrc[i];
  }

  // ---- in-block lin2 via MFMA
  {
    const int w = t >> 6, lane = t & 63;
    const int m = lane & 15, quad = lane >> 4;
    f16x8 a[2][2];
#pragma unroll
    for (int ti = 0; ti < 2; ti++){
      const f16* arow = hmid + (size_t)(gs * 256 + (2 * w + ti) * 16 + m) * 64;
      a[ti][0] = *(const f16x8*)(arow + quad * 8);
      a[ti][1] = *(const f16x8*)(arow + 32 + quad * 8);
    }
#pragma unroll
    for (int H = 0; H < 2; H++){
      const int n = H * 16 + m;
      f16x8 b0, b1;
#pragma unroll
      for (int j = 0; j < 8; j++){
        b0[j] = (f16)Wl[(quad * 8 + j) * 32 + n];
        b1[j] = (f16)Wl[(32 + quad * 8 + j) * 32 + n];
      }
      const float bv = bl[n];
#pragma unroll
      for (int ti = 0; ti < 2; ti++){
        f32x4 acc = {0.f, 0.f, 0.f, 0.f};
        acc = __builtin_amdgcn_mfma_f32_16x16x32_f16(a[ti][0], b0, acc, 0, 0, 0);
        acc = __builtin_amdgcn_mfma_f32_16x16x32_f16(a[ti][1], b1, acc, 0, 0, 0);
#pragma unroll
        for (int r = 0; r < 4; r++)
          xl_s[((2 * w + ti) * 16 + quad * 4 + r) * 40 + n] = (f16)(acc[r] + bv);
      }
    }
    if (w < 4){
      const f16* arow = hmid + (size_t)(gs * 256 + lo + w * 16 + m) * 64;
      f16x8 c0 = *(const f16x8*)(arow + quad * 8);
      f16x8 c1 = *(const f16x8*)(arow + 32 + quad * 8);
#pragma unroll
      for (int H = 0; H < 2; H++){
        const int n = H * 16 + m;
        f16x8 b0, b1;
#pragma unroll
        for (int j = 0; j < 8; j++){
          b0[j] = (f16)Wr[(quad * 8 + j) * 32 + n];
          b1[j] = (f16)Wr[(32 + quad * 8 + j) * 32 + n];
        }
        const float bv = br[n];
        f32x4 acc = {0.f, 0.f, 0.f, 0.f};
        acc = __builtin_amdgcn_mfma_f32_16x16x32_f16(c0, b0, acc, 0, 0, 0);
        acc = __builtin_amdgcn_mfma_f32_16x16x32_f16(c1, b1, acc, 0, 0, 0);
#pragma unroll
        for (int r = 0; r < 4; r++)
          xr_s[(w * 16 + quad * 4 + r) * 40 + n] = (f16)(acc[r] + bv);
      }
    }
  }
  __syncthreads();
  // ---- degree-sort permutation
  if (t < 64){
    int v = deg_s[t], r = 0;
#pragma unroll 8
    for (int j = 0; j < 64; j++){
      int dj = deg_s[j];
      r += (dj < v) || (dj == v && j < t);
    }
    perm[r] = (unsigned char)t;
  }
  __syncthreads();

  // ---- 8 threads/dst (sorted): full 32-dim xr + att in regs
  const int pairi = perm[t >> 3], sub = t & 7, ln = lo + pairi;
  f16x2 xrh[16], atth[16];
  {
    const f16x8* xrp = (const f16x8*)&xr_s[pairi * 40];
#pragma unroll
    for (int q = 0; q < 4; q++){
      f16x8 v = xrp[q];
#pragma unroll
      for (int u = 0; u < 4; u++){
        xrh[q * 4 + u][0] = v[2 * u];
        xrh[q * 4 + u][1] = v[2 * u + 1];
      }
    }
#pragma unroll
    for (int i = 0; i < 16; i++){
      atth[i][0] = (f16)att[2 * i];
      atth[i][1] = (f16)att[2 * i + 1];
    }
  }

  // ---- scores: edge-split
  const int s0 = start_s[pairi];
  int sE = s0 + deg_s[pairi];
  if (sE > CAPQ) sE = CAPQ;
  float lmax = -3.0e38f;
  for (int idx = s0 + sub; idx < sE; idx += 8){
    int sl = src_s[idx];
    const f16x8* rp = (const f16x8*)&xl_s[(unsigned)sl * 40];
    float accs[4] = {0.f, 0.f, 0.f, 0.f};
#pragma unroll
    for (int blk = 0; blk < 4; blk++){
      f16x8 rv = rp[blk];
#pragma unroll
      for (int u = 0; u < 4; u++){
        f16x2 v = {rv[2 * u], rv[2 * u + 1]};
        v = v + xrh[blk * 4 + u];
        accs[u] = __builtin_amdgcn_fdot2(lrelu2(v), atth[blk * 4 + u], accs[u], false);
      }
    }
    float sc = (accs[0] + accs[1]) + (accs[2] + accs[3]);
    sc_s[idx] = sc;
    lmax = fmaxf(lmax, sc);
  }
  lmax = fmaxf(lmax, __shfl_xor(lmax, 1, 64));
  lmax = fmaxf(lmax, __shfl_xor(lmax, 2, 64));
  lmax = fmaxf(lmax, __shfl_xor(lmax, 4, 64));
  const float smax = lmax;
  float ssum = 0.f;
  for (int idx = s0 + sub; idx < sE; idx += 8){
    float w = __expf(sc_s[idx] - smax);
    ssum += w;
    sc_s[idx] = w;
  }
  ssum += __shfl_xor(ssum, 1, 64);
  ssum += __shfl_xor(ssum, 2, 64);
  ssum += __shfl_xor(ssum, 4, 64);
  float inv = 1.f / ssum;

  float acc[4];
#pragma unroll
  for (int c = 0; c < 4; c++) acc[c] = 0.f;
  {
    int sl = (s0 < sE) ? src_s[s0] : 0;
    f16x4 row = *(const f16x4*)&xl_s[(unsigned)sl * 40 + sub * 4];
    for (int idx = s0; idx < sE; idx++){
      int sln = (idx + 1 < sE) ? src_s[idx + 1] : 0;
      f16x4 rown = *(const f16x4*)&xl_s[(unsigned)sln * 40 + sub * 4];
      float w = sc_s[idx];
#pragma unroll
      for (int c = 0; c < 4; c++) acc[c] = fmaf(w, (float)row[c], acc[c]);
      row = rown;
    }
  }
  f16x4 o;
#pragma unroll
  for (int c = 0; c < 4; c++)
    o[c] = (f16)(acc[c] * inv + bias[sub * 4 + c]);
  *(f16x4*)(hout + (size_t)(gs * 256 + ln) * 32 + sub * 4) = o;
}

// ---------------- simfused: sim MFMA + InstanceNorm + Sinkhorn + output ----
// grid 256 (batch=bid>>2, quarter=bid&3), 1024 thr (16 waves). The 4 blocks
// of a batch sync via device-scope arrival counters (all 256 blocks are
// co-resident: 16 waves/block, 256 CUs hold 512 such blocks).
__global__ __launch_bounds__(1024) void simfused(
    const f16* __restrict__ H,
    const float* __restrict__ gamma, const float* __restrict__ beta,
    unsigned* __restrict__ sb,      // [256*4] per-block stat slots
    unsigned* __restrict__ hb,      // [256*8192] per-block histograms
    unsigned* __restrict__ cnt,     // [128] arrival counters (zeroed by gat2)
    float* __restrict__ out)
{
  __shared__ float rb[16];
  __shared__ float bc[4];
  __shared__ unsigned hist[8192];
  const int bid = blockIdx.x;
  const int b = bid >> 2, q = bid & 3;
  const int t = threadIdx.x;
  const int w = t >> 6, lane = t & 63;
  const int m = lane & 15, quad = lane >> 4;
  const int rowT = q * 64 + (w & 3) * 16;
  const int colB = (w >> 2) * 64;

  const f16* h1 = H + (size_t)b * 256 * 32;
  const f16* h2 = H + (size_t)(64 + b) * 256 * 32;

  // ---- Phase A: sim quarter via MFMA (stays in regs)
  f16x8 av = *(const f16x8*)(h1 + (size_t)(rowT + m) * 32 + quad * 8);
  f32x4 c[4];
#pragma unroll
  for (int jj = 0; jj < 4; jj++){
    f16x8 bv = *(const f16x8*)(h2 + (size_t)(colB + jj * 16 + m) * 32 + quad * 8);
    f32x4 z = {0.f, 0.f, 0.f, 0.f};
    c[jj] = __builtin_amdgcn_mfma_f32_16x16x32_f16(av, bv, z, 0, 0, 0);
  }

  // ---- Phase B: block stats -> slot -> arrival -> merged affine params
  float sm = 0.f, s2 = 0.f, mn = 3.0e38f, mx = -3.0e38f;
#pragma unroll
  for (int jj = 0; jj < 4; jj++)
#pragma unroll
    for (int r = 0; r < 4; r++){
      float s = c[jj][r];
      sm += s; s2 = fmaf(s, s, s2);
      mn = fminf(mn, s); mx = fmaxf(mx, s);
    }
  sm = bsum16(sm, rb);
  s2 = bsum16(s2, rb);
  mn = bmin16(mn, rb);
  mx = bmax16(mx, rb);

  if (t == 0){
    sb[bid * 4 + 0] = __float_as_uint(sm);
    sb[bid * 4 + 1] = __float_as_uint(s2);
    sb[bid * 4 + 2] = fkey(mn);
    sb[bid * 4 + 3] = fkey(mx);
    __threadfence();
    atomicAdd(&cnt[b], 1u);
    while (ldacq(&cnt[b]) < 4u) __builtin_amdgcn_s_sleep(2);
    float sum = 0.f, ssq = 0.f;
    unsigned mnk = 0xFFFFFFFFu, mxk = 0u;
#pragma unroll
    for (int qq = 0; qq < 4; qq++){
      sum += __uint_as_float(ldacq(&sb[(b * 4 + qq) * 4 + 0]));
      ssq += __uint_as_float(ldacq(&sb[(b * 4 + qq) * 4 + 1]));
      mnk = min(mnk, ldacq(&sb[(b * 4 + qq) * 4 + 2]));
      mxk = max(mxk, ldacq(&sb[(b * 4 + qq) * 4 + 3]));
    }
    const float mu = sum * (1.f / 65536.f);
    const float var = ssq * (1.f / 65536.f) - mu * mu;
    const float a = gamma[0] * rsqrtf(var + 1e-5f);
    const float cc = beta[0] - a * mu;
    float mnn = a * fkinv(mnk) + cc, mxn = a * fkinv(mxk) + cc;
    if (a < 0.f){ float tmp = mnn; mnn = mxn; mxn = tmp; }
    bc[0] = 2.f * a;                         // al
    bc[1] = 2.f * cc - mnn - mxn;            // be
    bc[2] = fmaxf(mxn - mnn, 1e-12f);        // R
  }
  __syncthreads();
  const float al = bc[0], be = bc[1], R = bc[2];
  const float binscale = 4096.f / R;

  // ---- Phase C: LDS histogram; cache e^-z in regs; publish to global slot
  for (int i = t; i < 8192; i += 1024) hist[i] = 0u;
  __syncthreads();
#pragma unroll
  for (int jj = 0; jj < 4; jj++)
#pragma unroll
    for (int r = 0; r < 4; r++){
      float z = fmaf(al, c[jj][r], be);
      int bi = (int)fmaf(z, binscale, 4096.f);
      bi = min(max(bi, 0), 8191);
      atomicAdd(&hist[bi], 1u);
      c[jj][r] = __expf(-z);
    }
  __syncthreads();
  {
    unsigned* hout = hb + (size_t)bid * 8192;
#pragma unroll
    for (int j = 0; j < 8; j++) hout[t + j * 1024] = hist[t + j * 1024];
  }
  __threadfence();
  __syncthreads();
  if (t == 0){
    atomicAdd(&cnt[64 + b], 1u);
    while (ldacq(&cnt[64 + b]) < 4u) __builtin_amdgcn_s_sleep(2);
  }
  __syncthreads();

  // ---- Phase D: merge 4 histograms (8 bins/thread) + 5 bin-reductions
  const float wbin = R * (1.f / 4096.f);
  float ebs[8], cnts[8];
#pragma unroll
  for (int j = 0; j < 8; j++){
    float zc = fmaf((float)(t * 8 + j) + 0.5f, wbin, -R);
    ebs[j] = __expf(-zc);
    unsigned cv = hist[t * 8 + j];   // own block's bins from LDS
#pragma unroll
    for (int qq = 0; qq < 4; qq++)
      if (qq != q) cv += ldacq(&hb[(size_t)(b * 4 + qq) * 8192 + t * 8 + j]);
    cnts[j] = (float)cv;
  }

  float D = 0.f, S = 256.f, eD = 1.f;
  for (int p = 0; p < 5; p++){
    float loc = 0.f;
#pragma unroll
    for (int j = 0; j < 8; j++)
      loc += cnts[j] / (1.f + ebs[j] * eD);
    S = bsum16(loc, rb);
    if (p < 4){
      D += -5.5412635f /* log(256/65280) */ + __logf(65536.f - S) - __logf(S);
      eD = __expf(-D);
    }
  }

  // ---- Phase E: output from reg-cached e^-z
  const float scale = 256.f / S;
  float* ob = out + (size_t)b * 65536;
#pragma unroll
  for (int jj = 0; jj < 4; jj++)
#pragma unroll
    for (int r = 0; r < 4; r++){
      float v = scale / (1.f + c[jj][r] * eD);
      ob[(rowT + quad * 4 + r) * 256 + colB + jj * 16 + m] = fminf(v, 1.f);
    }
}

extern "C" void kernel_launch(void* const* d_in, const int* in_sizes, int n_in,
                              void* d_out, int out_size, void* d_ws, size_t ws_size,
                              hipStream_t stream)
{
  const float* x1   = (const float*)d_in[0];
  const float* x2   = (const float*)d_in[1];
  const int*   e1   = (const int*)d_in[2];
  const int*   e2   = (const int*)d_in[3];
  const float* Wl1  = (const float*)d_in[4];
  const float* Wr1  = (const float*)d_in[5];
  const float* bl1  = (const float*)d_in[6];
  const float* br1  = (const float*)d_in[7];
  const float* att1 = (const float*)d_in[8];
  const float* bias1= (const float*)d_in[9];
  const float* Wl2  = (const float*)d_in[10];
  const float* Wr2  = (const float*)d_in[11];
  const float* bl2  = (const float*)d_in[12];
  const float* br2  = (const float*)d_in[13];
  const float* att2 = (const float*)d_in[14];
  const float* bias2= (const float*)d_in[15];
  const float* gamma= (const float*)d_in[16];
  const float* beta = (const float*)d_in[17];

  char* ws = (char*)d_ws;
  f16* hmid = (f16*)ws;                                          // [0,4M)
  f16* hfin = (f16*)(ws + (size_t)4 * 1024 * 1024);              // [4M,6M)
  int* meta = (int*)(ws + (size_t)6 * 1024 * 1024);              // 256K
  unsigned char* srcs = (unsigned char*)(ws + (size_t)6 * 1024 * 1024 + 512 * 128 * 4);
  unsigned* sb  = (unsigned*)(ws + (size_t)8 * 1024 * 1024);     // 4K
  unsigned* cnt = (unsigned*)(ws + (size_t)8 * 1024 * 1024 + 8192);        // 512B
  unsigned* hb  = (unsigned*)(ws + (size_t)8 * 1024 * 1024 + 65536);       // 8M
  float* out = (float*)d_out;

  gat1<<<512, 512, 0, stream>>>(x1, x2, e1, e2, Wl1, Wr1, bl1, br1, att1, bias1,
                                hmid, meta, srcs);
  gat2<<<512, 512, 0, stream>>>(meta, srcs, hmid, Wl2, Wr2, bl2, br2, att2, bias2,
                                hfin, cnt);
  simfused<<<256, 1024, 0, stream>>>(hfin, gamma, beta, sb, hb, cnt, out);
}

// Round 9
// 188.110 us; speedup vs baseline: 5.2587x; 5.2587x over previous
//
#include <hip/hip_runtime.h>

#define NB 64
#define NN 256
#define IND 7
#define HIDD 64
#define OUTD 32
#define EPG 8192
#define ETOT 524288
#define CAPQ 2600     // CSR capacity per 64-dst quarter (mean 2112, ~12 sigma)
#define SRCPAD 2624   // CAPQ rounded to 16

typedef _Float16 f16;
typedef f16 f16x2 __attribute__((ext_vector_type(2)));
typedef f16 f16x4 __attribute__((ext_vector_type(4)));
typedef f16 f16x8 __attribute__((ext_vector_type(8)));
typedef float f32x4 __attribute__((ext_vector_type(4)));

// ---------------- block reductions for 16-wave blocks ----------------
__device__ __forceinline__ float bsum16(float v, float* rb){
#pragma unroll
  for (int o = 32; o > 0; o >>= 1) v += __shfl_xor(v, o, 64);
  __syncthreads();
  if ((threadIdx.x & 63) == 0) rb[threadIdx.x >> 6] = v;
  __syncthreads();
  float s = 0.f;
#pragma unroll
  for (int i = 0; i < 16; i++) s += rb[i];
  return s;
}
__device__ __forceinline__ float bmin16(float v, float* rb){
#pragma unroll
  for (int o = 32; o > 0; o >>= 1) v = fminf(v, __shfl_xor(v, o, 64));
  __syncthreads();
  if ((threadIdx.x & 63) == 0) rb[threadIdx.x >> 6] = v;
  __syncthreads();
  float s = rb[0];
#pragma unroll
  for (int i = 1; i < 16; i++) s = fminf(s, rb[i]);
  return s;
}
__device__ __forceinline__ float bmax16(float v, float* rb){
#pragma unroll
  for (int o = 32; o > 0; o >>= 1) v = fmaxf(v, __shfl_xor(v, o, 64));
  __syncthreads();
  if ((threadIdx.x & 63) == 0) rb[threadIdx.x >> 6] = v;
  __syncthreads();
  float s = rb[0];
#pragma unroll
  for (int i = 1; i < 16; i++) s = fmaxf(s, rb[i]);
  return s;
}

__device__ __forceinline__ f16x2 lrelu2(f16x2 s){
  const f16x2 k = {(f16)0.2f, (f16)0.2f};
  return __builtin_elementwise_max(s, s * k);
}
__device__ __forceinline__ f16x2 shfl_h2(f16x2 v, int lane){
  int i = __builtin_bit_cast(int, v);
  i = __shfl(i, lane, 64);
  return __builtin_bit_cast(f16x2, i);
}
// order-preserving float<->uint keys for min/max merging
__device__ __forceinline__ unsigned fkey(float f){
  unsigned b = __float_as_uint(f);
  return (b & 0x80000000u) ? ~b : (b | 0x80000000u);
}
__device__ __forceinline__ float fkinv(unsigned k){
  unsigned b = (k & 0x80000000u) ? (k ^ 0x80000000u) : ~k;
  return __uint_as_float(b);
}

// ---------------- GAT layer 1 + CSR build (fused, single edge read) --------
// grid 512: (gs=bid>>2, quarter=bid&3 -> 64 dsts), 512 thr, 8 thr/dst.
__global__ __launch_bounds__(512, 4) void gat1(
    const float* __restrict__ x1, const float* __restrict__ x2,
    const int* __restrict__ e1, const int* __restrict__ e2,
    const float* __restrict__ Wl, const float* __restrict__ Wr,
    const float* __restrict__ bl, const float* __restrict__ br,
    const float* __restrict__ att, const float* __restrict__ bias,
    f16* __restrict__ hmid,
    int* __restrict__ meta, unsigned char* __restrict__ srcs,
    unsigned* __restrict__ stats)
{
  __shared__ __align__(16) f16 xl_s[256 * 72];   // rows padded to 144B
  __shared__ float sc_s[CAPQ];
  __shared__ unsigned int src_su[SRCPAD / 4];
  __shared__ int deg_s[64], start_s[64], cnt_s[64];
  __shared__ unsigned char perm[64];
  unsigned char* src_s = (unsigned char*)src_su;

  const int bid = blockIdx.x;
  const int gs = bid >> 2, lo = (bid & 3) * 64;
  const int side = gs >> 6, g = gs & 63;
  const float* x = side ? x2 : x1;
  const int* eb = side ? e2 : e1;
  const int* es = eb + g * EPG;
  const int* ed = eb + ETOT + g * EPG;
  const int t = threadIdx.x;

  // zero simk's stat accumulators (workspace is poisoned before every call)
  if (bid == 0 && t < 256) stats[t] = ((t & 3) == 2) ? 0xFFFFFFFFu : 0u;

  if (t < 64) deg_s[t] = 0;

  // ---- single global edge read -> registers (packed dst<<8|src)
  unsigned short epk[17];
  int nE = 0;
#pragma unroll
  for (int i = 0; i < 17; i++){
    int e = t + i * 512;
    if (e < EPG + 256){
      int sl, dl;
      if (e < EPG){ sl = es[e] & 255; dl = ed[e] & 255; }
      else { sl = dl = e - EPG; }
      epk[i] = (unsigned short)((dl << 8) | sl);
      nE = i + 1;
    }
  }

  // ---- xl = x@Wl + bl: thread t -> node t>>1, dim-half t&1 (32 dims), f16 LDS
  {
    const int node = t >> 1, dh = t & 1;
    float xv[IND];
    const float* xr_ = x + (g * 256 + node) * IND;
#pragma unroll
    for (int k = 0; k < IND; k++) xv[k] = xr_[k];
#pragma unroll
    for (int ch = 0; ch < 4; ch++){
      f16x8 o;
#pragma unroll
      for (int j = 0; j < 8; j++){
        int dd = dh * 32 + ch * 8 + j;
        float a = bl[dd];
#pragma unroll
        for (int k = 0; k < IND; k++) a = fmaf(xv[k], Wl[k * HIDD + dd], a);
        o[j] = (f16)a;
      }
      *(f16x8*)&xl_s[node * 72 + dh * 32 + ch * 8] = o;
    }
  }
  __syncthreads();   // deg zero + xl_s visible

  // ---- CSR count pass (from regs)
#pragma unroll
  for (int i = 0; i < 17; i++) if (i < nE){
    int r = (epk[i] >> 8) - lo;
    if ((unsigned)r < 64u) atomicAdd(&deg_s[r], 1);
  }
  __syncthreads();
  // ---- scan + meta + degree-sort permutation
  if (t < 64){
    int v = deg_s[t], s = v;
#pragma unroll
    for (int off = 1; off < 64; off <<= 1){
      int u = __shfl_up(s, off, 64);
      if (t >= off) s += u;
    }
    start_s[t] = s - v;
    cnt_s[t] = s - v;
    meta[bid * 128 + t] = s - v;
    meta[bid * 128 + 64 + t] = v;
    int r = 0;
#pragma unroll 8
    for (int j = 0; j < 64; j++){
      int dj = deg_s[j];
      r += (dj < v) || (dj == v && j < t);
    }
    perm[r] = (unsigned char)t;
  }
  __syncthreads();
  // ---- fill pass (from regs)
#pragma unroll
  for (int i = 0; i < 17; i++) if (i < nE){
    int dl = epk[i] >> 8, r = dl - lo;
    if ((unsigned)r < 64u){
      int p = atomicAdd(&cnt_s[r], 1);
      if (p < CAPQ) src_s[p] = (unsigned char)(epk[i] & 255);
    }
  }
  __syncthreads();
  // ---- dump CSR srcs to global for gat2 (coalesced u32)
  {
    int ttl = start_s[63] + deg_s[63];
    if (ttl > CAPQ) ttl = CAPQ;
    unsigned int* gsrc = (unsigned int*)(srcs + (size_t)bid * SRCPAD);
    int nw = (ttl + 3) >> 2;
    for (int i = t; i < nw; i += 512) gsrc[i] = src_su[i];
  }

  // ---- 8 threads/dst (degree-sorted): my 8 xr dims, assemble 64 via shfl
  const int pairi = perm[t >> 3], sub = t & 7, ln = lo + pairi;
  f16x2 m[4], am[4];
  {
    float xv[IND];
    const float* xq = x + (g * 256 + ln) * IND;
#pragma unroll
    for (int k = 0; k < IND; k++) xv[k] = xq[k];
#pragma unroll
    for (int c = 0; c < 4; c++){
#pragma unroll
      for (int u = 0; u < 2; u++){
        int dd = sub * 8 + 2 * c + u;
        float a = br[dd];
#pragma unroll
        for (int k = 0; k < IND; k++) a = fmaf(xv[k], Wr[k * HIDD + dd], a);
        m[c][u] = (f16)a;
        am[c][u] = (f16)att[dd];
      }
    }
  }
  f16x2 xrh[32], atth[32];
  {
    const int base = (t & 63) & ~7;
#pragma unroll
    for (int ss = 0; ss < 8; ss++){
#pragma unroll
      for (int c = 0; c < 4; c++){
        xrh[ss * 4 + c] = shfl_h2(m[c], base + ss);
        atth[ss * 4 + c] = shfl_h2(am[c], base + ss);
      }
    }
  }

  // ---- scores: edge-split (thread handles every-8th edge, full 64 dims)
  const int s0 = start_s[pairi];
  int sE = s0 + deg_s[pairi];
  if (sE > CAPQ) sE = CAPQ;
  float lmax = -3.0e38f;
  for (int idx = s0 + sub; idx < sE; idx += 8){
    int sl = src_s[idx];
    const f16x8* rp = (const f16x8*)&xl_s[(unsigned)sl * 72];
    float accs[4] = {0.f, 0.f, 0.f, 0.f};
#pragma unroll
    for (int blk = 0; blk < 8; blk++){
      f16x8 rv = rp[blk];
#pragma unroll
      for (int u = 0; u < 4; u++){
        f16x2 v = {rv[2 * u], rv[2 * u + 1]};
        v = v + xrh[blk * 4 + u];
        accs[u] = __builtin_amdgcn_fdot2(lrelu2(v), atth[blk * 4 + u], accs[u], false);
      }
    }
    float sc = (accs[0] + accs[1]) + (accs[2] + accs[3]);
    sc_s[idx] = sc;
    lmax = fmaxf(lmax, sc);
  }
  lmax = fmaxf(lmax, __shfl_xor(lmax, 1, 64));
  lmax = fmaxf(lmax, __shfl_xor(lmax, 2, 64));
  lmax = fmaxf(lmax, __shfl_xor(lmax, 4, 64));
  const float smax = lmax;
  // ---- softmax weights
  float ssum = 0.f;
  for (int idx = s0 + sub; idx < sE; idx += 8){
    float w = __expf(sc_s[idx] - smax);
    ssum += w;
    sc_s[idx] = w;
  }
  ssum += __shfl_xor(ssum, 1, 64);
  ssum += __shfl_xor(ssum, 2, 64);
  ssum += __shfl_xor(ssum, 4, 64);
  float inv = 1.f / ssum;
  // ---- aggregate alpha * xl[src], dim-split 8 ways
  float acc[8];
#pragma unroll
  for (int c = 0; c < 8; c++) acc[c] = 0.f;
  {
    int sl = (s0 < sE) ? src_s[s0] : 0;
    f16x8 row = *(const f16x8*)&xl_s[(unsigned)sl * 72 + sub * 8];
    for (int idx = s0; idx < sE; idx++){
      int sln = (idx + 1 < sE) ? src_s[idx + 1] : 0;
      f16x8 rown = *(const f16x8*)&xl_s[(unsigned)sln * 72 + sub * 8];
      float w = sc_s[idx];
#pragma unroll
      for (int c = 0; c < 8; c++) acc[c] = fmaf(w, (float)row[c], acc[c]);
      row = rown;
    }
  }
  f16x8 o;
#pragma unroll
  for (int c = 0; c < 8; c++)
    o[c] = (f16)fmaxf(acc[c] * inv + bias[sub * 8 + c], 0.f);
  *(f16x8*)(hmid + (size_t)(gs * 256 + ln) * 64 + sub * 8) = o;
}

// ---------------- GAT layer 2 + lin2 (fused, degree-sorted) ----------------
__global__ __launch_bounds__(512, 4) void gat2(
    const int* __restrict__ meta, const unsigned char* __restrict__ srcs,
    const f16* __restrict__ hmid,
    const float* __restrict__ Wl, const float* __restrict__ Wr,
    const float* __restrict__ bl, const float* __restrict__ br,
    const float* __restrict__ att, const float* __restrict__ bias,
    f16* __restrict__ hout)
{
  __shared__ __align__(16) f16 xl_s[256 * 40];   // rows padded to 80B
  __shared__ __align__(16) f16 xr_s[64 * 40];
  __shared__ float sc_s[CAPQ];
  __shared__ unsigned int src_su[SRCPAD / 4];
  __shared__ int start_s[64], deg_s[64];
  __shared__ unsigned char perm[64];
  unsigned char* src_s = (unsigned char*)src_su;

  const int bid = blockIdx.x;
  const int gs = bid >> 2, lo = (bid & 3) * 64;
  const int t = threadIdx.x;

  // ---- CSR load (global -> LDS)
  if (t < 64){
    start_s[t] = meta[bid * 128 + t];
    deg_s[t] = meta[bid * 128 + 64 + t];
  }
  {
    int ttl = meta[bid * 128 + 63] + meta[bid * 128 + 64 + 63];
    if (ttl > CAPQ) ttl = CAPQ;
    const unsigned int* gsrc = (const unsigned int*)(srcs + (size_t)bid * SRCPAD);
    int nw = (ttl + 3) >> 2;
    for (int i = t; i < nw; i += 512) src_su[i] = gsrc[i];
  }

  // ---- in-block lin2 via MFMA
  {
    const int w = t >> 6, lane = t & 63;
    const int m = lane & 15, quad = lane >> 4;
    f16x8 a[2][2];
#pragma unroll
    for (int ti = 0; ti < 2; ti++){
      const f16* arow = hmid + (size_t)(gs * 256 + (2 * w + ti) * 16 + m) * 64;
      a[ti][0] = *(const f16x8*)(arow + quad * 8);
      a[ti][1] = *(const f16x8*)(arow + 32 + quad * 8);
    }
#pragma unroll
    for (int H = 0; H < 2; H++){
      const int n = H * 16 + m;
      f16x8 b0, b1;
#pragma unroll
      for (int j = 0; j < 8; j++){
        b0[j] = (f16)Wl[(quad * 8 + j) * 32 + n];
        b1[j] = (f16)Wl[(32 + quad * 8 + j) * 32 + n];
      }
      const float bv = bl[n];
#pragma unroll
      for (int ti = 0; ti < 2; ti++){
        f32x4 acc = {0.f, 0.f, 0.f, 0.f};
        acc = __builtin_amdgcn_mfma_f32_16x16x32_f16(a[ti][0], b0, acc, 0, 0, 0);
        acc = __builtin_amdgcn_mfma_f32_16x16x32_f16(a[ti][1], b1, acc, 0, 0, 0);
#pragma unroll
        for (int r = 0; r < 4; r++)
          xl_s[((2 * w + ti) * 16 + quad * 4 + r) * 40 + n] = (f16)(acc[r] + bv);
      }
    }
    if (w < 4){
      const f16* arow = hmid + (size_t)(gs * 256 + lo + w * 16 + m) * 64;
      f16x8 c0 = *(const f16x8*)(arow + quad * 8);
      f16x8 c1 = *(const f16x8*)(arow + 32 + quad * 8);
#pragma unroll
      for (int H = 0; H < 2; H++){
        const int n = H * 16 + m;
        f16x8 b0, b1;
#pragma unroll
        for (int j = 0; j < 8; j++){
          b0[j] = (f16)Wr[(quad * 8 + j) * 32 + n];
          b1[j] = (f16)Wr[(32 + quad * 8 + j) * 32 + n];
        }
        const float bv = br[n];
        f32x4 acc = {0.f, 0.f, 0.f, 0.f};
        acc = __builtin_amdgcn_mfma_f32_16x16x32_f16(c0, b0, acc, 0, 0, 0);
        acc = __builtin_amdgcn_mfma_f32_16x16x32_f16(c1, b1, acc, 0, 0, 0);
#pragma unroll
        for (int r = 0; r < 4; r++)
          xr_s[(w * 16 + quad * 4 + r) * 40 + n] = (f16)(acc[r] + bv);
      }
    }
  }
  __syncthreads();
  // ---- degree-sort permutation
  if (t < 64){
    int v = deg_s[t], r = 0;
#pragma unroll 8
    for (int j = 0; j < 64; j++){
      int dj = deg_s[j];
      r += (dj < v) || (dj == v && j < t);
    }
    perm[r] = (unsigned char)t;
  }
  __syncthreads();

  // ---- 8 threads/dst (sorted): full 32-dim xr + att in regs
  const int pairi = perm[t >> 3], sub = t & 7, ln = lo + pairi;
  f16x2 xrh[16], atth[16];
  {
    const f16x8* xrp = (const f16x8*)&xr_s[pairi * 40];
#pragma unroll
    for (int q = 0; q < 4; q++){
      f16x8 v = xrp[q];
#pragma unroll
      for (int u = 0; u < 4; u++){
        xrh[q * 4 + u][0] = v[2 * u];
        xrh[q * 4 + u][1] = v[2 * u + 1];
      }
    }
#pragma unroll
    for (int i = 0; i < 16; i++){
      atth[i][0] = (f16)att[2 * i];
      atth[i][1] = (f16)att[2 * i + 1];
    }
  }

  // ---- scores: edge-split
  const int s0 = start_s[pairi];
  int sE = s0 + deg_s[pairi];
  if (sE > CAPQ) sE = CAPQ;
  float lmax = -3.0e38f;
  for (int idx = s0 + sub; idx < sE; idx += 8){
    int sl = src_s[idx];
    const f16x8* rp = (const f16x8*)&xl_s[(unsigned)sl * 40];
    float accs[4] = {0.f, 0.f, 0.f, 0.f};
#pragma unroll
    for (int blk = 0; blk < 4; blk++){
      f16x8 rv = rp[blk];
#pragma unroll
      for (int u = 0; u < 4; u++){
        f16x2 v = {rv[2 * u], rv[2 * u + 1]};
        v = v + xrh[blk * 4 + u];
        accs[u] = __builtin_amdgcn_fdot2(lrelu2(v), atth[blk * 4 + u], accs[u], false);
      }
    }
    float sc = (accs[0] + accs[1]) + (accs[2] + accs[3]);
    sc_s[idx] = sc;
    lmax = fmaxf(lmax, sc);
  }
  lmax = fmaxf(lmax, __shfl_xor(lmax, 1, 64));
  lmax = fmaxf(lmax, __shfl_xor(lmax, 2, 64));
  lmax = fmaxf(lmax, __shfl_xor(lmax, 4, 64));
  const float smax = lmax;
  float ssum = 0.f;
  for (int idx = s0 + sub; idx < sE; idx += 8){
    float w = __expf(sc_s[idx] - smax);
    ssum += w;
    sc_s[idx] = w;
  }
  ssum += __shfl_xor(ssum, 1, 64);
  ssum += __shfl_xor(ssum, 2, 64);
  ssum += __shfl_xor(ssum, 4, 64);
  float inv = 1.f / ssum;

  float acc[4];
#pragma unroll
  for (int c = 0; c < 4; c++) acc[c] = 0.f;
  {
    int sl = (s0 < sE) ? src_s[s0] : 0;
    f16x4 row = *(const f16x4*)&xl_s[(unsigned)sl * 40 + sub * 4];
    for (int idx = s0; idx < sE; idx++){
      int sln = (idx + 1 < sE) ? src_s[idx + 1] : 0;
      f16x4 rown = *(const f16x4*)&xl_s[(unsigned)sln * 40 + sub * 4];
      float w = sc_s[idx];
#pragma unroll
      for (int c = 0; c < 4; c++) acc[c] = fmaf(w, (float)row[c], acc[c]);
      row = rown;
    }
  }
  f16x4 o;
#pragma unroll
  for (int c = 0; c < 4; c++)
    o[c] = (f16)(acc[c] * inv + bias[sub * 4 + c]);
  *(f16x4*)(hout + (size_t)(gs * 256 + ln) * 32 + sub * 4) = o;
}

// ---------------- simk: sim quarter via MFMA -> f16 + stats atomics --------
// grid 256 (batch=bid>>2, quarter=bid&3), 1024 thr (16 waves).
__global__ __launch_bounds__(1024) void simk(
    const f16* __restrict__ H, f16* __restrict__ simh,
    unsigned* __restrict__ stats)
{
  __shared__ float rb[16];
  const int b = blockIdx.x >> 2, q = blockIdx.x & 3, t = threadIdx.x;
  const int w = t >> 6, lane = t & 63;
  const int m = lane & 15, quad = lane >> 4;
  const int rowT = q * 64 + (w & 3) * 16;
  const int colB = (w >> 2) * 64;

  const f16* h1 = H + (size_t)b * 256 * 32;
  const f16* h2 = H + (size_t)(64 + b) * 256 * 32;

  f16x8 av = *(const f16x8*)(h1 + (size_t)(rowT + m) * 32 + quad * 8);
  f32x4 c[4];
#pragma unroll
  for (int jj = 0; jj < 4; jj++){
    f16x8 bv = *(const f16x8*)(h2 + (size_t)(colB + jj * 16 + m) * 32 + quad * 8);
    f32x4 z = {0.f, 0.f, 0.f, 0.f};
    c[jj] = __builtin_amdgcn_mfma_f32_16x16x32_f16(av, bv, z, 0, 0, 0);
  }

  float sm = 0.f, s2 = 0.f, mn = 3.0e38f, mx = -3.0e38f;
  f16* ob = simh + (size_t)b * 65536;
#pragma unroll
  for (int jj = 0; jj < 4; jj++)
#pragma unroll
    for (int r = 0; r < 4; r++){
      float s = c[jj][r];
      sm += s; s2 = fmaf(s, s, s2);
      mn = fminf(mn, s); mx = fmaxf(mx, s);
      ob[(rowT + quad * 4 + r) * 256 + colB + jj * 16 + m] = (f16)s;
    }
  sm = bsum16(sm, rb);
  s2 = bsum16(s2, rb);
  mn = bmin16(mn, rb);
  mx = bmax16(mx, rb);
  if (t == 0){
    atomicAdd((float*)&stats[b * 4 + 0], sm);
    atomicAdd((float*)&stats[b * 4 + 1], s2);
    atomicMin(&stats[b * 4 + 2], fkey(mn));
    atomicMax(&stats[b * 4 + 3], fkey(mx));
  }
}

// ---------------- sinkoutk: histogram Sinkhorn + output (per batch) --------
// grid 64, 1024 thr. Reads f16 sim once (e^-z cached in regs), writes f32 out.
__global__ __launch_bounds__(1024) void sinkoutk(
    const f16* __restrict__ simh, const unsigned* __restrict__ stats,
    const float* __restrict__ gamma, const float* __restrict__ beta,
    float* __restrict__ out)
{
  __shared__ float rb[16];
  __shared__ unsigned int hist[8192];
  const int b = blockIdx.x, t = threadIdx.x;

  const float sum = __uint_as_float(stats[b * 4 + 0]);
  const float ssq = __uint_as_float(stats[b * 4 + 1]);
  const float mn = fkinv(stats[b * 4 + 2]);
  const float mx = fkinv(stats[b * 4 + 3]);

  const float mu = sum * (1.f / 65536.f);
  const float var = ssq * (1.f / 65536.f) - mu * mu;
  const float a = gamma[0] * rsqrtf(var + 1e-5f);
  const float cc = beta[0] - a * mu;
  float mnn = a * mn + cc, mxn = a * mx + cc;
  if (a < 0.f){ float tmp = mnn; mnn = mxn; mxn = tmp; }
  const float al = 2.f * a;
  const float be = 2.f * cc - mnn - mxn;
  const float R = fmaxf(mxn - mnn, 1e-12f);       // z in [-R, R]
  const float binscale = 4096.f / R;

  for (int i = t; i < 8192; i += 1024) hist[i] = 0u;
  __syncthreads();
  // ---- histogram + cache e^-z (64 values/thread, coalesced f16x8 loads)
  const f16x8* sp = (const f16x8*)(simh + (size_t)b * 65536);
  float ez[64];
#pragma unroll
  for (int ch = 0; ch < 8; ch++){
    f16x8 v = sp[ch * 1024 + t];
#pragma unroll
    for (int u = 0; u < 8; u++){
      float z = fmaf(al, (float)v[u], be);
      int bi = (int)fmaf(z, binscale, 4096.f);
      bi = min(max(bi, 0), 8191);
      atomicAdd(&hist[bi], 1u);
      ez[ch * 8 + u] = __expf(-z);
    }
  }
  __syncthreads();

  // ---- 5 S_p reductions over bins (8 bins/thread)
  const float wbin = R * (1.f / 4096.f);
  float ebs[8], cnts[8];
#pragma unroll
  for (int j = 0; j < 8; j++){
    float zc = fmaf((float)(t * 8 + j) + 0.5f, wbin, -R);
    ebs[j] = __expf(-zc);
    cnts[j] = (float)hist[t * 8 + j];
  }

  float D = 0.f, S = 256.f, eD = 1.f;
  for (int p = 0; p < 5; p++){
    float loc = 0.f;
#pragma unroll
    for (int j = 0; j < 8; j++)
      loc += cnts[j] / (1.f + ebs[j] * eD);
    S = bsum16(loc, rb);
    if (p < 4){
      D += -5.5412635f /* log(256/65280) */ + __logf(65536.f - S) - __logf(S);
      eD = __expf(-D);
    }
  }

  // ---- output from reg-cached e^-z (same linear layout as the loads)
  const float scale = 256.f / S;
  f32x4* ob = (f32x4*)(out + (size_t)b * 65536);
#pragma unroll
  for (int ch = 0; ch < 8; ch++){
    f32x4 o0, o1;
#pragma unroll
    for (int u = 0; u < 4; u++){
      o0[u] = fminf(scale / (1.f + ez[ch * 8 + u] * eD), 1.f);
      o1[u] = fminf(scale / (1.f + ez[ch * 8 + 4 + u] * eD), 1.f);
    }
    ob[(ch * 1024 + t) * 2] = o0;
    ob[(ch * 1024 + t) * 2 + 1] = o1;
  }
}

extern "C" void kernel_launch(void* const* d_in, const int* in_sizes, int n_in,
                              void* d_out, int out_size, void* d_ws, size_t ws_size,
                              hipStream_t stream)
{
  const float* x1   = (const float*)d_in[0];
  const float* x2   = (const float*)d_in[1];
  const int*   e1   = (const int*)d_in[2];
  const int*   e2   = (const int*)d_in[3];
  const float* Wl1  = (const float*)d_in[4];
  const float* Wr1  = (const float*)d_in[5];
  const float* bl1  = (const float*)d_in[6];
  const float* br1  = (const float*)d_in[7];
  const float* att1 = (const float*)d_in[8];
  const float* bias1= (const float*)d_in[9];
  const float* Wl2  = (const float*)d_in[10];
  const float* Wr2  = (const float*)d_in[11];
  const float* bl2  = (const float*)d_in[12];
  const float* br2  = (const float*)d_in[13];
  const float* att2 = (const float*)d_in[14];
  const float* bias2= (const float*)d_in[15];
  const float* gamma= (const float*)d_in[16];
  const float* beta = (const float*)d_in[17];

  // ws (~10 MB): hfin [0,2M); hmid [2M,6M); meta [6M,+256K); srcs [+256K,+1.6M);
  // simh [2M+8M? no:] simh overlays dead hmid+meta+srcs at [2M,10M) AFTER gat2;
  // stats at [10M,+1K).
  char* ws = (char*)d_ws;
  f16* hfin = (f16*)ws;                                          // [0,2M)
  f16* hmid = (f16*)(ws + (size_t)2 * 1024 * 1024);              // [2M,6M) dead after gat2
  int* meta = (int*)(ws + (size_t)6 * 1024 * 1024);              // dead after gat2
  unsigned char* srcs = (unsigned char*)(ws + (size_t)6 * 1024 * 1024 + 512 * 128 * 4);
  f16* simh = (f16*)(ws + (size_t)2 * 1024 * 1024);              // [2M,10M) overlays the dead regions
  unsigned* stats = (unsigned*)(ws + (size_t)10 * 1024 * 1024);  // 1K
  float* out = (float*)d_out;

  gat1<<<512, 512, 0, stream>>>(x1, x2, e1, e2, Wl1, Wr1, bl1, br1, att1, bias1,
                                hmid, meta, srcs, stats);
  gat2<<<512, 512, 0, stream>>>(meta, srcs, hmid, Wl2, Wr2, bl2, br2, att2, bias2, hfin);
  simk<<<256, 1024, 0, stream>>>(hfin, simh, stats);
  sinkoutk<<<64, 1024, 0, stream>>>(simh, stats, gamma, beta, out);
}

// Round 11
// 181.415 us; speedup vs baseline: 5.4528x; 1.0369x over previous
//
#include <hip/hip_runtime.h>

#define NB 64
#define NN 256
#define IND 7
#define HIDD 64
#define OUTD 32
#define EPG 8192
#define ETOT 524288
#define CAPQ 2600     // CSR capacity per 64-dst quarter (mean 2112, ~12 sigma)
#define SRCPAD 2624   // CAPQ rounded to 16

typedef _Float16 f16;
typedef f16 f16x2 __attribute__((ext_vector_type(2)));
typedef f16 f16x4 __attribute__((ext_vector_type(4)));
typedef f16 f16x8 __attribute__((ext_vector_type(8)));
typedef float f32x4 __attribute__((ext_vector_type(4)));

// ---------------- block reductions for 16-wave blocks ----------------
__device__ __forceinline__ float bsum16(float v, float* rb){
#pragma unroll
  for (int o = 32; o > 0; o >>= 1) v += __shfl_xor(v, o, 64);
  __syncthreads();
  if ((threadIdx.x & 63) == 0) rb[threadIdx.x >> 6] = v;
  __syncthreads();
  float s = 0.f;
#pragma unroll
  for (int i = 0; i < 16; i++) s += rb[i];
  return s;
}
__device__ __forceinline__ float bmin16(float v, float* rb){
#pragma unroll
  for (int o = 32; o > 0; o >>= 1) v = fminf(v, __shfl_xor(v, o, 64));
  __syncthreads();
  if ((threadIdx.x & 63) == 0) rb[threadIdx.x >> 6] = v;
  __syncthreads();
  float s = rb[0];
#pragma unroll
  for (int i = 1; i < 16; i++) s = fminf(s, rb[i]);
  return s;
}
__device__ __forceinline__ float bmax16(float v, float* rb){
#pragma unroll
  for (int o = 32; o > 0; o >>= 1) v = fmaxf(v, __shfl_xor(v, o, 64));
  __syncthreads();
  if ((threadIdx.x & 63) == 0) rb[threadIdx.x >> 6] = v;
  __syncthreads();
  float s = rb[0];
#pragma unroll
  for (int i = 1; i < 16; i++) s = fmaxf(s, rb[i]);
  return s;
}

__device__ __forceinline__ f16x2 lrelu2(f16x2 s){
  const f16x2 k = {(f16)0.2f, (f16)0.2f};
  return __builtin_elementwise_max(s, s * k);
}
__device__ __forceinline__ f16x2 shfl_h2(f16x2 v, int lane){
  int i = __builtin_bit_cast(int, v);
  i = __shfl(i, lane, 64);
  return __builtin_bit_cast(f16x2, i);
}
// order-preserving float<->uint keys for min/max merging
__device__ __forceinline__ unsigned fkey(float f){
  unsigned b = __float_as_uint(f);
  return (b & 0x80000000u) ? ~b : (b | 0x80000000u);
}
__device__ __forceinline__ float fkinv(unsigned k){
  unsigned b = (k & 0x80000000u) ? (k ^ 0x80000000u) : ~k;
  return __uint_as_float(b);
}

// ---------------- GAT layer 1 + CSR build (fused, single edge read) --------
// grid 512, XCD-swizzled: gs = bid&127, quarter = bid>>7 (same-graph blocks
// share an XCD residue -> edge list fetched once per XCD L2). 8 thr/dst.
// CSR stored at slot `bid` (swizzled order); gat2 uses the SAME geometry and
// reads slot blockIdx.x directly — indices match by construction.
// Softmax WITHOUT max-subtraction (scores bounded, f32 exp safe): exp fused
// into the score loop, separate weight pass eliminated.
__global__ __launch_bounds__(512, 4) void gat1(
    const float* __restrict__ x1, const float* __restrict__ x2,
    const int* __restrict__ e1, const int* __restrict__ e2,
    const float* __restrict__ Wl, const float* __restrict__ Wr,
    const float* __restrict__ bl, const float* __restrict__ br,
    const float* __restrict__ att, const float* __restrict__ bias,
    f16* __restrict__ hmid,
    int* __restrict__ meta, unsigned char* __restrict__ srcs,
    unsigned* __restrict__ stats)
{
  __shared__ __align__(16) f16 xl_s[256 * 72];   // rows padded to 144B
  __shared__ float sc_s[CAPQ];
  __shared__ unsigned int src_su[SRCPAD / 4];
  __shared__ int deg_s[64], start_s[64], cnt_s[64];
  __shared__ unsigned char perm[64];
  unsigned char* src_s = (unsigned char*)src_su;

  const int bid = blockIdx.x;
  const int gs = bid & 127, lo = (bid >> 7) * 64;
  const int side = gs >> 6, g = gs & 63;
  const float* x = side ? x2 : x1;
  const int* eb = side ? e2 : e1;
  const int* es = eb + g * EPG;
  const int* ed = eb + ETOT + g * EPG;
  const int t = threadIdx.x;

  // zero simk's stat accumulators (workspace is poisoned before every call)
  if (bid == 0 && t < 256) stats[t] = ((t & 3) == 2) ? 0xFFFFFFFFu : 0u;

  if (t < 64) deg_s[t] = 0;

  // ---- single global edge read -> registers (packed dst<<8|src)
  unsigned short epk[17];
  int nE = 0;
#pragma unroll
  for (int i = 0; i < 17; i++){
    int e = t + i * 512;
    if (e < EPG + 256){
      int sl, dl;
      if (e < EPG){ sl = es[e] & 255; dl = ed[e] & 255; }
      else { sl = dl = e - EPG; }
      epk[i] = (unsigned short)((dl << 8) | sl);
      nE = i + 1;
    }
  }

  // ---- xl = x@Wl + bl: thread t -> node t>>1, dim-half t&1 (32 dims), f16 LDS
  {
    const int node = t >> 1, dh = t & 1;
    float xv[IND];
    const float* xr_ = x + (g * 256 + node) * IND;
#pragma unroll
    for (int k = 0; k < IND; k++) xv[k] = xr_[k];
#pragma unroll
    for (int ch = 0; ch < 4; ch++){
      f16x8 o;
#pragma unroll
      for (int j = 0; j < 8; j++){
        int dd = dh * 32 + ch * 8 + j;
        float a = bl[dd];
#pragma unroll
        for (int k = 0; k < IND; k++) a = fmaf(xv[k], Wl[k * HIDD + dd], a);
        o[j] = (f16)a;
      }
      *(f16x8*)&xl_s[node * 72 + dh * 32 + ch * 8] = o;
    }
  }
  __syncthreads();   // deg zero + xl_s visible

  // ---- CSR count pass (from regs)
#pragma unroll
  for (int i = 0; i < 17; i++) if (i < nE){
    int r = (epk[i] >> 8) - lo;
    if ((unsigned)r < 64u) atomicAdd(&deg_s[r], 1);
  }
  __syncthreads();
  // ---- scan + meta + degree-sort permutation
  if (t < 64){
    int v = deg_s[t], s = v;
#pragma unroll
    for (int off = 1; off < 64; off <<= 1){
      int u = __shfl_up(s, off, 64);
      if (t >= off) s += u;
    }
    start_s[t] = s - v;
    cnt_s[t] = s - v;
    meta[bid * 128 + t] = s - v;
    meta[bid * 128 + 64 + t] = v;
    int r = 0;
#pragma unroll 8
    for (int j = 0; j < 64; j++){
      int dj = deg_s[j];
      r += (dj < v) || (dj == v && j < t);
    }
    perm[r] = (unsigned char)t;
  }
  __syncthreads();
  // ---- fill pass (from regs)
#pragma unroll
  for (int i = 0; i < 17; i++) if (i < nE){
    int dl = epk[i] >> 8, r = dl - lo;
    if ((unsigned)r < 64u){
      int p = atomicAdd(&cnt_s[r], 1);
      if (p < CAPQ) src_s[p] = (unsigned char)(epk[i] & 255);
    }
  }
  __syncthreads();
  // ---- dump CSR srcs to global for gat2 (coalesced u32)
  {
    int ttl = start_s[63] + deg_s[63];
    if (ttl > CAPQ) ttl = CAPQ;
    unsigned int* gsrc = (unsigned int*)(srcs + (size_t)bid * SRCPAD);
    int nw = (ttl + 3) >> 2;
    for (int i = t; i < nw; i += 512) gsrc[i] = src_su[i];
  }

  // ---- 8 threads/dst (degree-sorted): my 8 xr dims, assemble 64 via shfl
  const int pairi = perm[t >> 3], sub = t & 7, ln = lo + pairi;
  f16x2 m[4], am[4];
  {
    float xv[IND];
    const float* xq = x + (g * 256 + ln) * IND;
#pragma unroll
    for (int k = 0; k < IND; k++) xv[k] = xq[k];
#pragma unroll
    for (int c = 0; c < 4; c++){
#pragma unroll
      for (int u = 0; u < 2; u++){
        int dd = sub * 8 + 2 * c + u;
        float a = br[dd];
#pragma unroll
        for (int k = 0; k < IND; k++) a = fmaf(xv[k], Wr[k * HIDD + dd], a);
        m[c][u] = (f16)a;
        am[c][u] = (f16)att[dd];
      }
    }
  }
  f16x2 xrh[32], atth[32];
  {
    const int base = (t & 63) & ~7;
#pragma unroll
    for (int ss = 0; ss < 8; ss++){
#pragma unroll
      for (int c = 0; c < 4; c++){
        xrh[ss * 4 + c] = shfl_h2(m[c], base + ss);
        atth[ss * 4 + c] = shfl_h2(am[c], base + ss);
      }
    }
  }

  // ---- scores + exp fused: edge-split (each thread every-8th edge, 64 dims)
  const int s0 = start_s[pairi];
  int sE = s0 + deg_s[pairi];
  if (sE > CAPQ) sE = CAPQ;
  float ssum = 0.f;
  for (int idx = s0 + sub; idx < sE; idx += 8){
    int sl = src_s[idx];
    const f16x8* rp = (const f16x8*)&xl_s[(unsigned)sl * 72];
    float accs[4] = {0.f, 0.f, 0.f, 0.f};
#pragma unroll
    for (int blk = 0; blk < 8; blk++){
      f16x8 rv = rp[blk];
#pragma unroll
      for (int u = 0; u < 4; u++){
        f16x2 v = {rv[2 * u], rv[2 * u + 1]};
        v = v + xrh[blk * 4 + u];
        accs[u] = __builtin_amdgcn_fdot2(lrelu2(v), atth[blk * 4 + u], accs[u], false);
      }
    }
    float w = __expf((accs[0] + accs[1]) + (accs[2] + accs[3]));
    sc_s[idx] = w;
    ssum += w;
  }
  ssum += __shfl_xor(ssum, 1, 64);
  ssum += __shfl_xor(ssum, 2, 64);
  ssum += __shfl_xor(ssum, 4, 64);
  float inv = 1.f / ssum;
  // ---- aggregate alpha * xl[src], dim-split 8 ways
  float acc[8];
#pragma unroll
  for (int c = 0; c < 8; c++) acc[c] = 0.f;
  {
    int sl = (s0 < sE) ? src_s[s0] : 0;
    f16x8 row = *(const f16x8*)&xl_s[(unsigned)sl * 72 + sub * 8];
    for (int idx = s0; idx < sE; idx++){
      int sln = (idx + 1 < sE) ? src_s[idx + 1] : 0;
      f16x8 rown = *(const f16x8*)&xl_s[(unsigned)sln * 72 + sub * 8];
      float w = sc_s[idx];
#pragma unroll
      for (int c = 0; c < 8; c++) acc[c] = fmaf(w, (float)row[c], acc[c]);
      row = rown;
    }
  }
  f16x8 o;
#pragma unroll
  for (int c = 0; c < 8; c++)
    o[c] = (f16)fmaxf(acc[c] * inv + bias[sub * 8 + c], 0.f);
  *(f16x8*)(hmid + (size_t)(gs * 256 + ln) * 64 + sub * 8) = o;
}

// ---------------- GAT layer 2 + lin2 (fused, degree-sorted) ----------------
// Same grid/swizzle as gat1; CSR slot = blockIdx.x (matches gat1's store).
__global__ __launch_bounds__(512, 4) void gat2(
    const int* __restrict__ meta, const unsigned char* __restrict__ srcs,
    const f16* __restrict__ hmid,
    const float* __restrict__ Wl, const float* __restrict__ Wr,
    const float* __restrict__ bl, const float* __restrict__ br,
    const float* __restrict__ att, const float* __restrict__ bias,
    f16* __restrict__ hout)
{
  __shared__ __align__(16) f16 xl_s[256 * 40];   // rows padded to 80B
  __shared__ __align__(16) f16 xr_s[64 * 40];
  __shared__ float sc_s[CAPQ];
  __shared__ unsigned int src_su[SRCPAD / 4];
  __shared__ int start_s[64], deg_s[64];
  __shared__ unsigned char perm[64];
  unsigned char* src_s = (unsigned char*)src_su;

  const int bid = blockIdx.x;                    // same mapping as gat1
  const int gs = bid & 127, lo = (bid >> 7) * 64;
  const int t = threadIdx.x;

  // ---- CSR load (global -> LDS)
  if (t < 64){
    start_s[t] = meta[bid * 128 + t];
    deg_s[t] = meta[bid * 128 + 64 + t];
  }
  {
    int ttl = meta[bid * 128 + 63] + meta[bid * 128 + 64 + 63];
    if (ttl > CAPQ) ttl = CAPQ;
    const unsigned int* gsrc = (const unsigned int*)(srcs + (size_t)bid * SRCPAD);
    int nw = (ttl + 3) >> 2;
    for (int i = t; i < nw; i += 512) src_su[i] = gsrc[i];
  }

  // ---- in-block lin2 via MFMA
  {
    const int w = t >> 6, lane = t & 63;
    const int m = lane & 15, quad = lane >> 4;
    f16x8 a[2][2];
#pragma unroll
    for (int ti = 0; ti < 2; ti++){
      const f16* arow = hmid + (size_t)(gs * 256 + (2 * w + ti) * 16 + m) * 64;
      a[ti][0] = *(const f16x8*)(arow + quad * 8);
      a[ti][1] = *(const f16x8*)(arow + 32 + quad * 8);
    }
#pragma unroll
    for (int H = 0; H < 2; H++){
      const int n = H * 16 + m;
      f16x8 b0, b1;
#pragma unroll
      for (int j = 0; j < 8; j++){
        b0[j] = (f16)Wl[(quad * 8 + j) * 32 + n];
        b1[j] = (f16)Wl[(32 + quad * 8 + j) * 32 + n];
      }
      const float bv = bl[n];
#pragma unroll
      for (int ti = 0; ti < 2; ti++){
        f32x4 acc = {0.f, 0.f, 0.f, 0.f};
        acc = __builtin_amdgcn_mfma_f32_16x16x32_f16(a[ti][0], b0, acc, 0, 0, 0);
        acc = __builtin_amdgcn_mfma_f32_16x16x32_f16(a[ti][1], b1, acc, 0, 0, 0);
#pragma unroll
        for (int r = 0; r < 4; r++)
          xl_s[((2 * w + ti) * 16 + quad * 4 + r) * 40 + n] = (f16)(acc[r] + bv);
      }
    }
    if (w < 4){
      const f16* arow = hmid + (size_t)(gs * 256 + lo + w * 16 + m) * 64;
      f16x8 c0 = *(const f16x8*)(arow + quad * 8);
      f16x8 c1 = *(const f16x8*)(arow + 32 + quad * 8);
#pragma unroll
      for (int H = 0; H < 2; H++){
        const int n = H * 16 + m;
        f16x8 b0, b1;
#pragma unroll
        for (int j = 0; j < 8; j++){
          b0[j] = (f16)Wr[(quad * 8 + j) * 32 + n];
          b1[j] = (f16)Wr[(32 + quad * 8 + j) * 32 + n];
        }
        const float bv = br[n];
        f32x4 acc = {0.f, 0.f, 0.f, 0.f};
        acc = __builtin_amdgcn_mfma_f32_16x16x32_f16(c0, b0, acc, 0, 0, 0);
        acc = __builtin_amdgcn_mfma_f32_16x16x32_f16(c1, b1, acc, 0, 0, 0);
#pragma unroll
        for (int r = 0; r < 4; r++)
          xr_s[(w * 16 + quad * 4 + r) * 40 + n] = (f16)(acc[r] + bv);
      }
    }
  }
  __syncthreads();
  // ---- degree-sort permutation
  if (t < 64){
    int v = deg_s[t], r = 0;
#pragma unroll 8
    for (int j = 0; j < 64; j++){
      int dj = deg_s[j];
      r += (dj < v) || (dj == v && j < t);
    }
    perm[r] = (unsigned char)t;
  }
  __syncthreads();

  // ---- 8 threads/dst (sorted): full 32-dim xr + att in regs
  const int pairi = perm[t >> 3], sub = t & 7, ln = lo + pairi;
  f16x2 xrh[16], atth[16];
  {
    const f16x8* xrp = (const f16x8*)&xr_s[pairi * 40];
#pragma unroll
    for (int q = 0; q < 4; q++){
      f16x8 v = xrp[q];
#pragma unroll
      for (int u = 0; u < 4; u++){
        xrh[q * 4 + u][0] = v[2 * u];
        xrh[q * 4 + u][1] = v[2 * u + 1];
      }
    }
#pragma unroll
    for (int i = 0; i < 16; i++){
      atth[i][0] = (f16)att[2 * i];
      atth[i][1] = (f16)att[2 * i + 1];
    }
  }

  // ---- scores + exp fused: edge-split
  const int s0 = start_s[pairi];
  int sE = s0 + deg_s[pairi];
  if (sE > CAPQ) sE = CAPQ;
  float ssum = 0.f;
  for (int idx = s0 + sub; idx < sE; idx += 8){
    int sl = src_s[idx];
    const f16x8* rp = (const f16x8*)&xl_s[(unsigned)sl * 40];
    float accs[4] = {0.f, 0.f, 0.f, 0.f};
#pragma unroll
    for (int blk = 0; blk < 4; blk++){
      f16x8 rv = rp[blk];
#pragma unroll
      for (int u = 0; u < 4; u++){
        f16x2 v = {rv[2 * u], rv[2 * u + 1]};
        v = v + xrh[blk * 4 + u];
        accs[u] = __builtin_amdgcn_fdot2(lrelu2(v), atth[blk * 4 + u], accs[u], false);
      }
    }
    float w = __expf((accs[0] + accs[1]) + (accs[2] + accs[3]));
    sc_s[idx] = w;
    ssum += w;
  }
  ssum += __shfl_xor(ssum, 1, 64);
  ssum += __shfl_xor(ssum, 2, 64);
  ssum += __shfl_xor(ssum, 4, 64);
  float inv = 1.f / ssum;

  float acc[4];
#pragma unroll
  for (int c = 0; c < 4; c++) acc[c] = 0.f;
  {
    int sl = (s0 < sE) ? src_s[s0] : 0;
    f16x4 row = *(const f16x4*)&xl_s[(unsigned)sl * 40 + sub * 4];
    for (int idx = s0; idx < sE; idx++){
      int sln = (idx + 1 < sE) ? src_s[idx + 1] : 0;
      f16x4 rown = *(const f16x4*)&xl_s[(unsigned)sln * 40 + sub * 4];
      float w = sc_s[idx];
#pragma unroll
      for (int c = 0; c < 4; c++) acc[c] = fmaf(w, (float)row[c], acc[c]);
      row = rown;
    }
  }
  f16x4 o;
#pragma unroll
  for (int c = 0; c < 4; c++)
    o[c] = (f16)(acc[c] * inv + bias[sub * 4 + c]);
  *(f16x4*)(hout + (size_t)(gs * 256 + ln) * 32 + sub * 4) = o;
}

// ---------------- simk: sim quarter via MFMA -> f16 + stats atomics --------
// grid 256 XCD-swizzled (b = bid&63, q = bid>>6), 1024 thr (16 waves).
__global__ __launch_bounds__(1024) void simk(
    const f16* __restrict__ H, f16* __restrict__ simh,
    unsigned* __restrict__ stats)
{
  __shared__ float rb[16];
  const int b = blockIdx.x & 63, q = blockIdx.x >> 6, t = threadIdx.x;
  const int w = t >> 6, lane = t & 63;
  const int m = lane & 15, quad = lane >> 4;
  const int rowT = q * 64 + (w & 3) * 16;
  const int colB = (w >> 2) * 64;

  const f16* h1 = H + (size_t)b * 256 * 32;
  const f16* h2 = H + (size_t)(64 + b) * 256 * 32;

  f16x8 av = *(const f16x8*)(h1 + (size_t)(rowT + m) * 32 + quad * 8);
  f32x4 c[4];
#pragma unroll
  for (int jj = 0; jj < 4; jj++){
    f16x8 bv = *(const f16x8*)(h2 + (size_t)(colB + jj * 16 + m) * 32 + quad * 8);
    f32x4 z = {0.f, 0.f, 0.f, 0.f};
    c[jj] = __builtin_amdgcn_mfma_f32_16x16x32_f16(av, bv, z, 0, 0, 0);
  }

  float sm = 0.f, s2 = 0.f, mn = 3.0e38f, mx = -3.0e38f;
  f16* ob = simh + (size_t)b * 65536;
#pragma unroll
  for (int jj = 0; jj < 4; jj++)
#pragma unroll
    for (int r = 0; r < 4; r++){
      float s = c[jj][r];
      sm += s; s2 = fmaf(s, s, s2);
      mn = fminf(mn, s); mx = fmaxf(mx, s);
      ob[(rowT + quad * 4 + r) * 256 + colB + jj * 16 + m] = (f16)s;
    }
  sm = bsum16(sm, rb);
  s2 = bsum16(s2, rb);
  mn = bmin16(mn, rb);
  mx = bmax16(mx, rb);
  if (t == 0){
    atomicAdd((float*)&stats[b * 4 + 0], sm);
    atomicAdd((float*)&stats[b * 4 + 1], s2);
    atomicMin(&stats[b * 4 + 2], fkey(mn));
    atomicMax(&stats[b * 4 + 3], fkey(mx));
  }
}

// ---------------- sinkk: per-batch histogram Sinkhorn scalars --------------
// grid 64, 1024 thr. Reads f16 sim once, emits {al, be+D, scale} per batch.
__global__ __launch_bounds__(1024) void sinkk(
    const f16* __restrict__ simh, const unsigned* __restrict__ stats,
    const float* __restrict__ gamma, const float* __restrict__ beta,
    float* __restrict__ res)
{
  __shared__ float rb[16];
  __shared__ unsigned int hist[8192];
  const int b = blockIdx.x, t = threadIdx.x;

  const float sum = __uint_as_float(stats[b * 4 + 0]);
  const float ssq = __uint_as_float(stats[b * 4 + 1]);
  const float mn = fkinv(stats[b * 4 + 2]);
  const float mx = fkinv(stats[b * 4 + 3]);

  const float mu = sum * (1.f / 65536.f);
  const float var = ssq * (1.f / 65536.f) - mu * mu;
  const float a = gamma[0] * rsqrtf(var + 1e-5f);
  const float cc = beta[0] - a * mu;
  float mnn = a * mn + cc, mxn = a * mx + cc;
  if (a < 0.f){ float tmp = mnn; mnn = mxn; mxn = tmp; }
  const float al = 2.f * a;
  const float be = 2.f * cc - mnn - mxn;
  const float R = fmaxf(mxn - mnn, 1e-12f);       // z in [-R, R]
  const float binscale = 4096.f / R;

  for (int i = t; i < 8192; i += 1024) hist[i] = 0u;
  __syncthreads();
  const f16x8* sp = (const f16x8*)(simh + (size_t)b * 65536);
#pragma unroll
  for (int ch = 0; ch < 8; ch++){
    f16x8 v = sp[ch * 1024 + t];
#pragma unroll
    for (int u = 0; u < 8; u++){
      float z = fmaf(al, (float)v[u], be);
      int bi = (int)fmaf(z, binscale, 4096.f);
      bi = min(max(bi, 0), 8191);
      atomicAdd(&hist[bi], 1u);
    }
  }
  __syncthreads();

  const float wbin = R * (1.f / 4096.f);
  float ebs[8], cnts[8];
#pragma unroll
  for (int j = 0; j < 8; j++){
    float zc = fmaf((float)(t * 8 + j) + 0.5f, wbin, -R);
    ebs[j] = __expf(-zc);
    cnts[j] = (float)hist[t * 8 + j];
  }

  float D = 0.f, S = 256.f, eD = 1.f;
  for (int p = 0; p < 5; p++){
    float loc = 0.f;
#pragma unroll
    for (int j = 0; j < 8; j++)
      loc += cnts[j] / (1.f + ebs[j] * eD);
    S = bsum16(loc, rb);
    if (p < 4){
      D += -5.5412635f /* log(256/65280) */ + __logf(65536.f - S) - __logf(S);
      eD = __expf(-D);
    }
  }
  if (t == 0){
    res[b * 4 + 0] = al;
    res[b * 4 + 1] = be + D;
    res[b * 4 + 2] = 256.f / S;
  }
}

// ---------------- outk: elementwise sigmoid+clip, full GPU -----------------
// grid 512 XCD-swizzled (b = bid&63, seg = bid>>6), 256 thr.
__global__ __launch_bounds__(256) void outk(
    const f16* __restrict__ simh, const float* __restrict__ res,
    float* __restrict__ out)
{
  const int b = blockIdx.x & 63, seg = blockIdx.x >> 6, t = threadIdx.x;
  const float al = res[b * 4 + 0];
  const float beD = res[b * 4 + 1];
  const float scale = res[b * 4 + 2];
  const f16x8* sp = (const f16x8*)(simh + (size_t)b * 65536 + seg * 8192);
  f32x4* ob = (f32x4*)(out + (size_t)b * 65536 + seg * 8192);
#pragma unroll
  for (int k = 0; k < 4; k++){
    f16x8 v = sp[k * 256 + t];
    f32x4 o0, o1;
#pragma unroll
    for (int u = 0; u < 4; u++){
      float z0 = fmaf(al, (float)v[u], beD);
      float z1 = fmaf(al, (float)v[4 + u], beD);
      o0[u] = fminf(scale / (1.f + __expf(-z0)), 1.f);
      o1[u] = fminf(scale / (1.f + __expf(-z1)), 1.f);
    }
    ob[(k * 256 + t) * 2] = o0;
    ob[(k * 256 + t) * 2 + 1] = o1;
  }
}

extern "C" void kernel_launch(void* const* d_in, const int* in_sizes, int n_in,
                              void* d_out, int out_size, void* d_ws, size_t ws_size,
                              hipStream_t stream)
{
  const float* x1   = (const float*)d_in[0];
  const float* x2   = (const float*)d_in[1];
  const int*   e1   = (const int*)d_in[2];
  const int*   e2   = (const int*)d_in[3];
  const float* Wl1  = (const float*)d_in[4];
  const float* Wr1  = (const float*)d_in[5];
  const float* bl1  = (const float*)d_in[6];
  const float* br1  = (const float*)d_in[7];
  const float* att1 = (const float*)d_in[8];
  const float* bias1= (const float*)d_in[9];
  const float* Wl2  = (const float*)d_in[10];
  const float* Wr2  = (const float*)d_in[11];
  const float* bl2  = (const float*)d_in[12];
  const float* br2  = (const float*)d_in[13];
  const float* att2 = (const float*)d_in[14];
  const float* bias2= (const float*)d_in[15];
  const float* gamma= (const float*)d_in[16];
  const float* beta = (const float*)d_in[17];

  // ws (~10 MB): hfin [0,2M); hmid [2M,6M) + meta/srcs [6M,7.6M) dead after
  // gat2 -> simh overlays [2M,10M); stats/res at [10M,+8K).
  char* ws = (char*)d_ws;
  f16* hfin = (f16*)ws;
  f16* hmid = (f16*)(ws + (size_t)2 * 1024 * 1024);
  int* meta = (int*)(ws + (size_t)6 * 1024 * 1024);
  unsigned char* srcs = (unsigned char*)(ws + (size_t)6 * 1024 * 1024 + 512 * 128 * 4);
  f16* simh = (f16*)(ws + (size_t)2 * 1024 * 1024);
  unsigned* stats = (unsigned*)(ws + (size_t)10 * 1024 * 1024);
  float* res = (float*)(ws + (size_t)10 * 1024 * 1024 + 4096);
  float* out = (float*)d_out;

  gat1<<<512, 512, 0, stream>>>(x1, x2, e1, e2, Wl1, Wr1, bl1, br1, att1, bias1,
                                hmid, meta, srcs, stats);
  gat2<<<512, 512, 0, stream>>>(meta, srcs, hmid, Wl2, Wr2, bl2, br2, att2, bias2, hfin);
  simk<<<256, 1024, 0, stream>>>(hfin, simh, stats);
  sinkk<<<64, 1024, 0, stream>>>(simh, stats, gamma, beta, res);
  outk<<<512, 256, 0, stream>>>(simh, res, out);
}

// Round 12
// 177.013 us; speedup vs baseline: 5.5884x; 1.0249x over previous
//
#include <hip/hip_runtime.h>

#define NB 64
#define NN 256
#define IND 7
#define HIDD 64
#define OUTD 32
#define EPG 8192
#define ETOT 524288
#define CAPQ 2600     // CSR capacity per 64-dst quarter (mean 2112, ~12 sigma)
#define SRCPAD 2624   // CAPQ rounded to 16

typedef _Float16 f16;
typedef f16 f16x2 __attribute__((ext_vector_type(2)));
typedef f16 f16x4 __attribute__((ext_vector_type(4)));
typedef f16 f16x8 __attribute__((ext_vector_type(8)));
typedef float f32x4 __attribute__((ext_vector_type(4)));

// ---------------- block reductions for 16-wave blocks ----------------
__device__ __forceinline__ float bsum16(float v, float* rb){
#pragma unroll
  for (int o = 32; o > 0; o >>= 1) v += __shfl_xor(v, o, 64);
  __syncthreads();
  if ((threadIdx.x & 63) == 0) rb[threadIdx.x >> 6] = v;
  __syncthreads();
  float s = 0.f;
#pragma unroll
  for (int i = 0; i < 16; i++) s += rb[i];
  return s;
}
__device__ __forceinline__ float bmin16(float v, float* rb){
#pragma unroll
  for (int o = 32; o > 0; o >>= 1) v = fminf(v, __shfl_xor(v, o, 64));
  __syncthreads();
  if ((threadIdx.x & 63) == 0) rb[threadIdx.x >> 6] = v;
  __syncthreads();
  float s = rb[0];
#pragma unroll
  for (int i = 1; i < 16; i++) s = fminf(s, rb[i]);
  return s;
}
__device__ __forceinline__ float bmax16(float v, float* rb){
#pragma unroll
  for (int o = 32; o > 0; o >>= 1) v = fmaxf(v, __shfl_xor(v, o, 64));
  __syncthreads();
  if ((threadIdx.x & 63) == 0) rb[threadIdx.x >> 6] = v;
  __syncthreads();
  float s = rb[0];
#pragma unroll
  for (int i = 1; i < 16; i++) s = fmaxf(s, rb[i]);
  return s;
}

__device__ __forceinline__ f16x2 lrelu2(f16x2 s){
  const f16x2 k = {(f16)0.2f, (f16)0.2f};
  return __builtin_elementwise_max(s, s * k);
}
__device__ __forceinline__ f16x2 shfl_h2(f16x2 v, int lane){
  int i = __builtin_bit_cast(int, v);
  i = __shfl(i, lane, 64);
  return __builtin_bit_cast(f16x2, i);
}

// ---------------- GAT layer 1 + CSR build (fused, single edge read) --------
// grid 512, XCD-swizzled: gs = bid&127, quarter = bid>>7. 8 thr/dst.
// CSR stored at slot `bid`; gat2 uses identical geometry, slot = blockIdx.x.
// Softmax without max-subtraction (scores bounded, f32 exp safe): exp fused
// into the score loop.
__global__ __launch_bounds__(512, 4) void gat1(
    const float* __restrict__ x1, const float* __restrict__ x2,
    const int* __restrict__ e1, const int* __restrict__ e2,
    const float* __restrict__ Wl, const float* __restrict__ Wr,
    const float* __restrict__ bl, const float* __restrict__ br,
    const float* __restrict__ att, const float* __restrict__ bias,
    f16* __restrict__ hmid,
    int* __restrict__ meta, unsigned char* __restrict__ srcs)
{
  __shared__ __align__(16) f16 xl_s[256 * 72];   // rows padded to 144B
  __shared__ float sc_s[CAPQ];
  __shared__ unsigned int src_su[SRCPAD / 4];
  __shared__ int deg_s[64], start_s[64], cnt_s[64];
  __shared__ unsigned char perm[64];
  unsigned char* src_s = (unsigned char*)src_su;

  const int bid = blockIdx.x;
  const int gs = bid & 127, lo = (bid >> 7) * 64;
  const int side = gs >> 6, g = gs & 63;
  const float* x = side ? x2 : x1;
  const int* eb = side ? e2 : e1;
  const int* es = eb + g * EPG;
  const int* ed = eb + ETOT + g * EPG;
  const int t = threadIdx.x;

  if (t < 64) deg_s[t] = 0;

  // ---- single global edge read -> registers (packed dst<<8|src)
  unsigned short epk[17];
  int nE = 0;
#pragma unroll
  for (int i = 0; i < 17; i++){
    int e = t + i * 512;
    if (e < EPG + 256){
      int sl, dl;
      if (e < EPG){ sl = es[e] & 255; dl = ed[e] & 255; }
      else { sl = dl = e - EPG; }
      epk[i] = (unsigned short)((dl << 8) | sl);
      nE = i + 1;
    }
  }

  // ---- xl = x@Wl + bl: thread t -> node t>>1, dim-half t&1 (32 dims), f16 LDS
  {
    const int node = t >> 1, dh = t & 1;
    float xv[IND];
    const float* xr_ = x + (g * 256 + node) * IND;
#pragma unroll
    for (int k = 0; k < IND; k++) xv[k] = xr_[k];
#pragma unroll
    for (int ch = 0; ch < 4; ch++){
      f16x8 o;
#pragma unroll
      for (int j = 0; j < 8; j++){
        int dd = dh * 32 + ch * 8 + j;
        float a = bl[dd];
#pragma unroll
        for (int k = 0; k < IND; k++) a = fmaf(xv[k], Wl[k * HIDD + dd], a);
        o[j] = (f16)a;
      }
      *(f16x8*)&xl_s[node * 72 + dh * 32 + ch * 8] = o;
    }
  }
  __syncthreads();   // deg zero + xl_s visible

  // ---- CSR count pass (from regs)
#pragma unroll
  for (int i = 0; i < 17; i++) if (i < nE){
    int r = (epk[i] >> 8) - lo;
    if ((unsigned)r < 64u) atomicAdd(&deg_s[r], 1);
  }
  __syncthreads();
  // ---- scan + meta + degree-sort permutation
  if (t < 64){
    int v = deg_s[t], s = v;
#pragma unroll
    for (int off = 1; off < 64; off <<= 1){
      int u = __shfl_up(s, off, 64);
      if (t >= off) s += u;
    }
    start_s[t] = s - v;
    cnt_s[t] = s - v;
    meta[bid * 128 + t] = s - v;
    meta[bid * 128 + 64 + t] = v;
    int r = 0;
#pragma unroll 8
    for (int j = 0; j < 64; j++){
      int dj = deg_s[j];
      r += (dj < v) || (dj == v && j < t);
    }
    perm[r] = (unsigned char)t;
  }
  __syncthreads();
  // ---- fill pass (from regs)
#pragma unroll
  for (int i = 0; i < 17; i++) if (i < nE){
    int dl = epk[i] >> 8, r = dl - lo;
    if ((unsigned)r < 64u){
      int p = atomicAdd(&cnt_s[r], 1);
      if (p < CAPQ) src_s[p] = (unsigned char)(epk[i] & 255);
    }
  }
  __syncthreads();
  // ---- dump CSR srcs to global for gat2 (coalesced u32)
  {
    int ttl = start_s[63] + deg_s[63];
    if (ttl > CAPQ) ttl = CAPQ;
    unsigned int* gsrc = (unsigned int*)(srcs + (size_t)bid * SRCPAD);
    int nw = (ttl + 3) >> 2;
    for (int i = t; i < nw; i += 512) gsrc[i] = src_su[i];
  }

  // ---- 8 threads/dst (degree-sorted): my 8 xr dims, assemble 64 via shfl
  const int pairi = perm[t >> 3], sub = t & 7, ln = lo + pairi;
  f16x2 m[4], am[4];
  {
    float xv[IND];
    const float* xq = x + (g * 256 + ln) * IND;
#pragma unroll
    for (int k = 0; k < IND; k++) xv[k] = xq[k];
#pragma unroll
    for (int c = 0; c < 4; c++){
#pragma unroll
      for (int u = 0; u < 2; u++){
        int dd = sub * 8 + 2 * c + u;
        float a = br[dd];
#pragma unroll
        for (int k = 0; k < IND; k++) a = fmaf(xv[k], Wr[k * HIDD + dd], a);
        m[c][u] = (f16)a;
        am[c][u] = (f16)att[dd];
      }
    }
  }
  f16x2 xrh[32], atth[32];
  {
    const int base = (t & 63) & ~7;
#pragma unroll
    for (int ss = 0; ss < 8; ss++){
#pragma unroll
      for (int c = 0; c < 4; c++){
        xrh[ss * 4 + c] = shfl_h2(m[c], base + ss);
        atth[ss * 4 + c] = shfl_h2(am[c], base + ss);
      }
    }
  }

  // ---- scores + exp fused: edge-split (each thread every-8th edge, 64 dims)
  const int s0 = start_s[pairi];
  int sE = s0 + deg_s[pairi];
  if (sE > CAPQ) sE = CAPQ;
  float ssum = 0.f;
  for (int idx = s0 + sub; idx < sE; idx += 8){
    int sl = src_s[idx];
    const f16x8* rp = (const f16x8*)&xl_s[(unsigned)sl * 72];
    float accs[4] = {0.f, 0.f, 0.f, 0.f};
#pragma unroll
    for (int blk = 0; blk < 8; blk++){
      f16x8 rv = rp[blk];
#pragma unroll
      for (int u = 0; u < 4; u++){
        f16x2 v = {rv[2 * u], rv[2 * u + 1]};
        v = v + xrh[blk * 4 + u];
        accs[u] = __builtin_amdgcn_fdot2(lrelu2(v), atth[blk * 4 + u], accs[u], false);
      }
    }
    float w = __expf((accs[0] + accs[1]) + (accs[2] + accs[3]));
    sc_s[idx] = w;
    ssum += w;
  }
  ssum += __shfl_xor(ssum, 1, 64);
  ssum += __shfl_xor(ssum, 2, 64);
  ssum += __shfl_xor(ssum, 4, 64);
  float inv = 1.f / ssum;
  // ---- aggregate alpha * xl[src], dim-split 8 ways
  float acc[8];
#pragma unroll
  for (int c = 0; c < 8; c++) acc[c] = 0.f;
  {
    int sl = (s0 < sE) ? src_s[s0] : 0;
    f16x8 row = *(const f16x8*)&xl_s[(unsigned)sl * 72 + sub * 8];
    for (int idx = s0; idx < sE; idx++){
      int sln = (idx + 1 < sE) ? src_s[idx + 1] : 0;
      f16x8 rown = *(const f16x8*)&xl_s[(unsigned)sln * 72 + sub * 8];
      float w = sc_s[idx];
#pragma unroll
      for (int c = 0; c < 8; c++) acc[c] = fmaf(w, (float)row[c], acc[c]);
      row = rown;
    }
  }
  f16x8 o;
#pragma unroll
  for (int c = 0; c < 8; c++)
    o[c] = (f16)fmaxf(acc[c] * inv + bias[sub * 8 + c], 0.f);
  *(f16x8*)(hmid + (size_t)(gs * 256 + ln) * 64 + sub * 8) = o;
}

// ---------------- GAT layer 2 + lin2 (fused, degree-sorted) ----------------
// Same grid/swizzle as gat1; CSR slot = blockIdx.x (matches gat1's store).
__global__ __launch_bounds__(512, 4) void gat2(
    const int* __restrict__ meta, const unsigned char* __restrict__ srcs,
    const f16* __restrict__ hmid,
    const float* __restrict__ Wl, const float* __restrict__ Wr,
    const float* __restrict__ bl, const float* __restrict__ br,
    const float* __restrict__ att, const float* __restrict__ bias,
    f16* __restrict__ hout)
{
  __shared__ __align__(16) f16 xl_s[256 * 40];   // rows padded to 80B
  __shared__ __align__(16) f16 xr_s[64 * 40];
  __shared__ float sc_s[CAPQ];
  __shared__ unsigned int src_su[SRCPAD / 4];
  __shared__ int start_s[64], deg_s[64];
  __shared__ unsigned char perm[64];
  unsigned char* src_s = (unsigned char*)src_su;

  const int bid = blockIdx.x;                    // same mapping as gat1
  const int gs = bid & 127, lo = (bid >> 7) * 64;
  const int t = threadIdx.x;

  // ---- CSR load (global -> LDS)
  if (t < 64){
    start_s[t] = meta[bid * 128 + t];
    deg_s[t] = meta[bid * 128 + 64 + t];
  }
  {
    int ttl = meta[bid * 128 + 63] + meta[bid * 128 + 64 + 63];
    if (ttl > CAPQ) ttl = CAPQ;
    const unsigned int* gsrc = (const unsigned int*)(srcs + (size_t)bid * SRCPAD);
    int nw = (ttl + 3) >> 2;
    for (int i = t; i < nw; i += 512) src_su[i] = gsrc[i];
  }

  // ---- in-block lin2 via MFMA
  {
    const int w = t >> 6, lane = t & 63;
    const int m = lane & 15, quad = lane >> 4;
    f16x8 a[2][2];
#pragma unroll
    for (int ti = 0; ti < 2; ti++){
      const f16* arow = hmid + (size_t)(gs * 256 + (2 * w + ti) * 16 + m) * 64;
      a[ti][0] = *(const f16x8*)(arow + quad * 8);
      a[ti][1] = *(const f16x8*)(arow + 32 + quad * 8);
    }
#pragma unroll
    for (int H = 0; H < 2; H++){
      const int n = H * 16 + m;
      f16x8 b0, b1;
#pragma unroll
      for (int j = 0; j < 8; j++){
        b0[j] = (f16)Wl[(quad * 8 + j) * 32 + n];
        b1[j] = (f16)Wl[(32 + quad * 8 + j) * 32 + n];
      }
      const float bv = bl[n];
#pragma unroll
      for (int ti = 0; ti < 2; ti++){
        f32x4 acc = {0.f, 0.f, 0.f, 0.f};
        acc = __builtin_amdgcn_mfma_f32_16x16x32_f16(a[ti][0], b0, acc, 0, 0, 0);
        acc = __builtin_amdgcn_mfma_f32_16x16x32_f16(a[ti][1], b1, acc, 0, 0, 0);
#pragma unroll
        for (int r = 0; r < 4; r++)
          xl_s[((2 * w + ti) * 16 + quad * 4 + r) * 40 + n] = (f16)(acc[r] + bv);
      }
    }
    if (w < 4){
      const f16* arow = hmid + (size_t)(gs * 256 + lo + w * 16 + m) * 64;
      f16x8 c0 = *(const f16x8*)(arow + quad * 8);
      f16x8 c1 = *(const f16x8*)(arow + 32 + quad * 8);
#pragma unroll
      for (int H = 0; H < 2; H++){
        const int n = H * 16 + m;
        f16x8 b0, b1;
#pragma unroll
        for (int j = 0; j < 8; j++){
          b0[j] = (f16)Wr[(quad * 8 + j) * 32 + n];
          b1[j] = (f16)Wr[(32 + quad * 8 + j) * 32 + n];
        }
        const float bv = br[n];
        f32x4 acc = {0.f, 0.f, 0.f, 0.f};
        acc = __builtin_amdgcn_mfma_f32_16x16x32_f16(c0, b0, acc, 0, 0, 0);
        acc = __builtin_amdgcn_mfma_f32_16x16x32_f16(c1, b1, acc, 0, 0, 0);
#pragma unroll
        for (int r = 0; r < 4; r++)
          xr_s[(w * 16 + quad * 4 + r) * 40 + n] = (f16)(acc[r] + bv);
      }
    }
  }
  __syncthreads();
  // ---- degree-sort permutation
  if (t < 64){
    int v = deg_s[t], r = 0;
#pragma unroll 8
    for (int j = 0; j < 64; j++){
      int dj = deg_s[j];
      r += (dj < v) || (dj == v && j < t);
    }
    perm[r] = (unsigned char)t;
  }
  __syncthreads();

  // ---- 8 threads/dst (sorted): full 32-dim xr + att in regs
  const int pairi = perm[t >> 3], sub = t & 7, ln = lo + pairi;
  f16x2 xrh[16], atth[16];
  {
    const f16x8* xrp = (const f16x8*)&xr_s[pairi * 40];
#pragma unroll
    for (int q = 0; q < 4; q++){
      f16x8 v = xrp[q];
#pragma unroll
      for (int u = 0; u < 4; u++){
        xrh[q * 4 + u][0] = v[2 * u];
        xrh[q * 4 + u][1] = v[2 * u + 1];
      }
    }
#pragma unroll
    for (int i = 0; i < 16; i++){
      atth[i][0] = (f16)att[2 * i];
      atth[i][1] = (f16)att[2 * i + 1];
    }
  }

  // ---- scores + exp fused: edge-split
  const int s0 = start_s[pairi];
  int sE = s0 + deg_s[pairi];
  if (sE > CAPQ) sE = CAPQ;
  float ssum = 0.f;
  for (int idx = s0 + sub; idx < sE; idx += 8){
    int sl = src_s[idx];
    const f16x8* rp = (const f16x8*)&xl_s[(unsigned)sl * 40];
    float accs[4] = {0.f, 0.f, 0.f, 0.f};
#pragma unroll
    for (int blk = 0; blk < 4; blk++){
      f16x8 rv = rp[blk];
#pragma unroll
      for (int u = 0; u < 4; u++){
        f16x2 v = {rv[2 * u], rv[2 * u + 1]};
        v = v + xrh[blk * 4 + u];
        accs[u] = __builtin_amdgcn_fdot2(lrelu2(v), atth[blk * 4 + u], accs[u], false);
      }
    }
    float w = __expf((accs[0] + accs[1]) + (accs[2] + accs[3]));
    sc_s[idx] = w;
    ssum += w;
  }
  ssum += __shfl_xor(ssum, 1, 64);
  ssum += __shfl_xor(ssum, 2, 64);
  ssum += __shfl_xor(ssum, 4, 64);
  float inv = 1.f / ssum;

  float acc[4];
#pragma unroll
  for (int c = 0; c < 4; c++) acc[c] = 0.f;
  {
    int sl = (s0 < sE) ? src_s[s0] : 0;
    f16x4 row = *(const f16x4*)&xl_s[(unsigned)sl * 40 + sub * 4];
    for (int idx = s0; idx < sE; idx++){
      int sln = (idx + 1 < sE) ? src_s[idx + 1] : 0;
      f16x4 rown = *(const f16x4*)&xl_s[(unsigned)sln * 40 + sub * 4];
      float w = sc_s[idx];
#pragma unroll
      for (int c = 0; c < 4; c++) acc[c] = fmaf(w, (float)row[c], acc[c]);
      row = rown;
    }
  }
  f16x4 o;
#pragma unroll
  for (int c = 0; c < 4; c++)
    o[c] = (f16)(acc[c] * inv + bias[sub * 4 + c]);
  *(f16x4*)(hout + (size_t)(gs * 256 + ln) * 32 + sub * 4) = o;
}

// ---------------- sinkk: MFMA sim (in regs) + stats + histogram Sinkhorn ---
// grid 64, 1024 thr (16 waves). One block per batch: wave w computes sim rows
// [w*16,w*16+16) x all 256 cols as 16 MFMA tiles (reg-resident). Stats via
// block reductions (no atomics), then 8192-bin LDS histogram -> res scalars.
__global__ __launch_bounds__(1024) void sinkk(
    const f16* __restrict__ H,
    const float* __restrict__ gamma, const float* __restrict__ beta,
    float* __restrict__ res)
{
  __shared__ float rb[16];
  __shared__ unsigned int hist[8192];
  const int b = blockIdx.x, t = threadIdx.x;
  const int w = t >> 6, lane = t & 63;
  const int m = lane & 15, quad = lane >> 4;

  const f16* h1 = H + (size_t)b * 256 * 32;
  const f16* h2 = H + (size_t)(64 + b) * 256 * 32;

  f16x8 av = *(const f16x8*)(h1 + (size_t)(w * 16 + m) * 32 + quad * 8);
  f32x4 c[16];
#pragma unroll
  for (int j = 0; j < 16; j++){
    f16x8 bv = *(const f16x8*)(h2 + (size_t)(j * 16 + m) * 32 + quad * 8);
    f32x4 z = {0.f, 0.f, 0.f, 0.f};
    c[j] = __builtin_amdgcn_mfma_f32_16x16x32_f16(av, bv, z, 0, 0, 0);
  }

  // ---- stats over reg-resident sim
  float sm = 0.f, s2 = 0.f, mn = 3.0e38f, mx = -3.0e38f;
#pragma unroll
  for (int j = 0; j < 16; j++)
#pragma unroll
    for (int r = 0; r < 4; r++){
      float s = c[j][r];
      sm += s; s2 = fmaf(s, s, s2);
      mn = fminf(mn, s); mx = fmaxf(mx, s);
    }
  sm = bsum16(sm, rb);
  s2 = bsum16(s2, rb);
  mn = bmin16(mn, rb);
  mx = bmax16(mx, rb);

  const float mu = sm * (1.f / 65536.f);
  const float var = s2 * (1.f / 65536.f) - mu * mu;
  const float a = gamma[0] * rsqrtf(var + 1e-5f);
  const float cc = beta[0] - a * mu;
  float mnn = a * mn + cc, mxn = a * mx + cc;
  if (a < 0.f){ float tmp = mnn; mnn = mxn; mxn = tmp; }
  const float al = 2.f * a;
  const float be = 2.f * cc - mnn - mxn;
  const float R = fmaxf(mxn - mnn, 1e-12f);       // z in [-R, R]
  const float binscale = 4096.f / R;

  // ---- histogram from f32 sim
  for (int i = t; i < 8192; i += 1024) hist[i] = 0u;
  __syncthreads();
#pragma unroll
  for (int j = 0; j < 16; j++)
#pragma unroll
    for (int r = 0; r < 4; r++){
      float z = fmaf(al, c[j][r], be);
      int bi = (int)fmaf(z, binscale, 4096.f);
      bi = min(max(bi, 0), 8191);
      atomicAdd(&hist[bi], 1u);
    }
  __syncthreads();

  // ---- 5 S_p reductions over bins (8 bins/thread)
  const float wbin = R * (1.f / 4096.f);
  float ebs[8], cnts[8];
#pragma unroll
  for (int j = 0; j < 8; j++){
    float zc = fmaf((float)(t * 8 + j) + 0.5f, wbin, -R);
    ebs[j] = __expf(-zc);
    cnts[j] = (float)hist[t * 8 + j];
  }

  float D = 0.f, S = 256.f, eD = 1.f;
  for (int p = 0; p < 5; p++){
    float loc = 0.f;
#pragma unroll
    for (int j = 0; j < 8; j++)
      loc += cnts[j] / (1.f + ebs[j] * eD);
    S = bsum16(loc, rb);
    if (p < 4){
      D += -5.5412635f /* log(256/65280) */ + __logf(65536.f - S) - __logf(S);
      eD = __expf(-D);
    }
  }
  if (t == 0){
    res[b * 4 + 0] = al;
    res[b * 4 + 1] = be + D;
    res[b * 4 + 2] = 256.f / S;
  }
}

// ---------------- outk: MFMA sim quarter + sigmoid + write, full GPU -------
// grid 256 XCD-swizzled (b = bid&63, q = bid>>6), 1024 thr (16 waves).
__global__ __launch_bounds__(1024) void outk(
    const f16* __restrict__ H, const float* __restrict__ res,
    float* __restrict__ out)
{
  const int b = blockIdx.x & 63, q = blockIdx.x >> 6, t = threadIdx.x;
  const int w = t >> 6, lane = t & 63;
  const int m = lane & 15, quad = lane >> 4;
  const int rowT = q * 64 + (w & 3) * 16;
  const int colB = (w >> 2) * 64;

  const float al = res[b * 4 + 0];
  const float beD = res[b * 4 + 1];
  const float scale = res[b * 4 + 2];

  const f16* h1 = H + (size_t)b * 256 * 32;
  const f16* h2 = H + (size_t)(64 + b) * 256 * 32;

  f16x8 av = *(const f16x8*)(h1 + (size_t)(rowT + m) * 32 + quad * 8);
  float* ob = out + (size_t)b * 65536;
#pragma unroll
  for (int jj = 0; jj < 4; jj++){
    f16x8 bv = *(const f16x8*)(h2 + (size_t)(colB + jj * 16 + m) * 32 + quad * 8);
    f32x4 z = {0.f, 0.f, 0.f, 0.f};
    f32x4 c = __builtin_amdgcn_mfma_f32_16x16x32_f16(av, bv, z, 0, 0, 0);
#pragma unroll
    for (int r = 0; r < 4; r++){
      float zz = fmaf(al, c[r], beD);
      float v = fminf(scale / (1.f + __expf(-zz)), 1.f);
      ob[(rowT + quad * 4 + r) * 256 + colB + jj * 16 + m] = v;
    }
  }
}

extern "C" void kernel_launch(void* const* d_in, const int* in_sizes, int n_in,
                              void* d_out, int out_size, void* d_ws, size_t ws_size,
                              hipStream_t stream)
{
  const float* x1   = (const float*)d_in[0];
  const float* x2   = (const float*)d_in[1];
  const int*   e1   = (const int*)d_in[2];
  const int*   e2   = (const int*)d_in[3];
  const float* Wl1  = (const float*)d_in[4];
  const float* Wr1  = (const float*)d_in[5];
  const float* bl1  = (const float*)d_in[6];
  const float* br1  = (const float*)d_in[7];
  const float* att1 = (const float*)d_in[8];
  const float* bias1= (const float*)d_in[9];
  const float* Wl2  = (const float*)d_in[10];
  const float* Wr2  = (const float*)d_in[11];
  const float* bl2  = (const float*)d_in[12];
  const float* br2  = (const float*)d_in[13];
  const float* att2 = (const float*)d_in[14];
  const float* bias2= (const float*)d_in[15];
  const float* gamma= (const float*)d_in[16];
  const float* beta = (const float*)d_in[17];

  // ws (~8.1 MB): hfin [0,2M); hmid [2M,6M); meta [6M,+256K);
  // srcs [+256K,+1.6M); res [8M,+1K).
  char* ws = (char*)d_ws;
  f16* hfin = (f16*)ws;
  f16* hmid = (f16*)(ws + (size_t)2 * 1024 * 1024);
  int* meta = (int*)(ws + (size_t)6 * 1024 * 1024);
  unsigned char* srcs = (unsigned char*)(ws + (size_t)6 * 1024 * 1024 + 512 * 128 * 4);
  float* res = (float*)(ws + (size_t)8 * 1024 * 1024);
  float* out = (float*)d_out;

  gat1<<<512, 512, 0, stream>>>(x1, x2, e1, e2, Wl1, Wr1, bl1, br1, att1, bias1,
                                hmid, meta, srcs);
  gat2<<<512, 512, 0, stream>>>(meta, srcs, hmid, Wl2, Wr2, bl2, br2, att2, bias2, hfin);
  sinkk<<<64, 1024, 0, stream>>>(hfin, gamma, beta, res);
  outk<<<256, 1024, 0, stream>>>(hfin, res, out);
}